// Round 11
// baseline (830.069 us; speedup 1.0000x reference)
//
#include <hip/hip_runtime.h>
#include <hip/hip_bf16.h>
#include <math.h>

#define NN 262144
#define NE 2097152
#define NG 8192
#define THREADS 256

typedef __hip_bfloat16 bf16;
typedef __attribute__((ext_vector_type(8))) short short8v;   // 8 bf16 (4 VGPRs)
typedef __attribute__((ext_vector_type(4))) float f32x4;

static __device__ __forceinline__ float lrelu(float x){ return x > 0.f ? x : 0.01f*x; }
static __device__ __forceinline__ float eluf(float x){ return x > 0.f ? x : expm1f(x); }
static __device__ __forceinline__ float sigm(float x){ return 1.f/(1.f+expf(-x)); }
static __device__ __forceinline__ float b2f(bf16 v){ return __bfloat162float(v); }
static __device__ __forceinline__ bf16 f2b(float v){ return __float2bfloat16(v); }
// bit-reinterpret a raw bf16 (held in a short) to float — NEVER value-convert!
static __device__ __forceinline__ float s2f(short s){
  return __uint_as_float(((unsigned int)(unsigned short)s) << 16);
}

static __device__ __forceinline__ unsigned short bfbits(float f){
  union { bf16 b; unsigned short s; } u; u.b = f2b(f); return u.s;
}
static __device__ __forceinline__ unsigned int pack2(float lo, float hi){
  return (unsigned int)bfbits(lo) | ((unsigned int)bfbits(hi) << 16);
}

static __device__ __forceinline__ float redsum32(float t){
  #pragma unroll
  for (int o = 16; o > 0; o >>= 1) t += __shfl_xor(t, o, 32);
  return t;
}
static __device__ __forceinline__ float redmax32(float t){
  #pragma unroll
  for (int o = 16; o > 0; o >>= 1) t = fmaxf(t, __shfl_xor(t, o, 32));
  return t;
}

// GRU fused helper for the tiny readout kernel (32 lanes = one row)
static __device__ __forceinline__ float gru_relu(float hv, float xv, int c,
    const float* __restrict__ wih, const float* __restrict__ whh,
    const float* __restrict__ bih, const float* __restrict__ bhh){
  float gr = bih[c], gz = bih[32+c], gn = bih[64+c];
  float hr = bhh[c], hz = bhh[32+c], hn = bhh[64+c];
  #pragma unroll 8
  for (int k = 0; k < 32; k++){
    float hk = __shfl(hv, k, 32);
    float xk = __shfl(xv, k, 32);
    gr += hk*wih[(     c)*32 + k];
    gz += hk*wih[(32 + c)*32 + k];
    gn += hk*wih[(64 + c)*32 + k];
    hr += xk*whh[(     c)*32 + k];
    hz += xk*whh[(32 + c)*32 + k];
    hn += xk*whh[(64 + c)*32 + k];
  }
  float r = sigm(gr + hr), z = sigm(gz + hz);
  float nn2 = tanhf(gn + r*hn);
  return fmaxf((1.f - z)*nn2 + z*xv, 0.f);
}

__global__ __launch_bounds__(THREADS) void k_filli(int* __restrict__ p, int v, int n){
  int i = blockIdx.x*THREADS + threadIdx.x;
  if (i < n) p[i] = v;
}

// ---- weight transposes + readout q, once per call ----
__global__ void k_prep(const float* __restrict__ lin1_w, const float* __restrict__ g_lin1_w,
    const float* __restrict__ g_lin2_w, const float* __restrict__ a_lin_w,
    const float* __restrict__ m_lin_w, const float* __restrict__ m_att_dst,
    float* __restrict__ lin1T, float* __restrict__ g1T, float* __restrict__ g2T,
    float* __restrict__ aT, float* __restrict__ mT, float* __restrict__ q){
  int t = threadIdx.x;
  for (int i = t; i < 54*32; i += 256){ int k = i>>5, c = i&31; lin1T[i] = lin1_w[c*54+k]; }
  for (int i = t; i < 1024; i += 256){
    int k = i>>5, c = i&31;
    g1T[i] = g_lin1_w[c*33+k];
    g2T[i] = g_lin2_w[c*32+k];
    aT[i]  = a_lin_w[c*32+k];
    mT[i]  = m_lin_w[c*32+k];
  }
  if (t < 32){
    float acc = 0.f;
    #pragma unroll
    for (int c2 = 0; c2 < 32; c2++) acc += m_att_dst[c2]*m_lin_w[c2*32+t];
    q[t] = acc;
  }
}

// ---- fused atom embedding + GATEConv node precompute ----
// lane-per-channel; transposed weights -> coalesced loads AND stores
__global__ __launch_bounds__(THREADS) void k_embed(const float* __restrict__ xin,
    const float* __restrict__ lin1T, const float* __restrict__ b,
    const float* __restrict__ g1T, const float* __restrict__ g2T,
    const float* __restrict__ attr_r, float* __restrict__ X,
    bf16* __restrict__ u, bf16* __restrict__ v, float* __restrict__ nr){
  int gid = blockIdx.x*THREADS + threadIdx.x;
  int n = gid >> 5, c = gid & 31;
  const float* xr = xin + (size_t)n*54;
  float acc = b[c];
  #pragma unroll
  for (int k = 0; k < 54; k++) acc += xr[k]*lin1T[k*32+c];
  float o = lrelu(acc);
  X[(size_t)n*32 + c] = o;                       // coalesced 4B/lane
  float rp = redsum32(o*attr_r[c]);
  if (c == 0) nr[n] = rp;
  float ua = 0.f, va = 0.f;
  #pragma unroll
  for (int k = 0; k < 32; k++){
    float xk = __shfl(o, k, 32);
    ua += xk*g1T[k*32+c];
    va += xk*g2T[k*32+c];
  }
  u[(size_t)n*32 + c] = f2b(ua);                 // coalesced 2B/lane
  v[(size_t)n*32 + c] = f2b(va);
}

// ---------------- CSR build ----------------
// histogram + within-dst rank in ONE atomic pass
__global__ __launch_bounds__(THREADS) void k_histrank(const int* __restrict__ ei,
    int* __restrict__ hist, int* __restrict__ rank){
  int e = blockIdx.x*THREADS + threadIdx.x;
  rank[e] = atomicAdd(hist + ei[NE + e], 1);
}

__global__ __launch_bounds__(THREADS) void k_scan1(const int* __restrict__ hist,
    int* __restrict__ rowptr, int* __restrict__ btot){
  __shared__ int sh[THREADS];
  int i = blockIdx.x*THREADS + threadIdx.x;
  int v = hist[i];
  sh[threadIdx.x] = v; __syncthreads();
  #pragma unroll
  for (int off = 1; off < THREADS; off <<= 1){
    int t = (threadIdx.x >= off) ? sh[threadIdx.x - off] : 0;
    __syncthreads(); sh[threadIdx.x] += t; __syncthreads();
  }
  rowptr[i] = sh[threadIdx.x] - v;
  if (threadIdx.x == THREADS-1) btot[blockIdx.x] = sh[THREADS-1];
}

__global__ __launch_bounds__(1024) void k_scan2(int* __restrict__ btot){
  __shared__ int sh[1024];
  int i = threadIdx.x;
  int v = btot[i];
  sh[i] = v; __syncthreads();
  for (int off = 1; off < 1024; off <<= 1){
    int t = (i >= off) ? sh[i - off] : 0;
    __syncthreads(); sh[i] += t; __syncthreads();
  }
  btot[i] = sh[i] - v;  // exclusive
}

__global__ __launch_bounds__(THREADS) void k_scan3(int* __restrict__ rowptr,
    const int* __restrict__ btot){
  int i = blockIdx.x*THREADS + threadIdx.x;
  rowptr[i] = rowptr[i] + btot[i >> 8];
  if (i == 0) rowptr[NN] = NE;
}

// ATOMIC-FREE placement: pos = rowptr[dst] + rank[e]; single 8B scattered store
__global__ __launch_bounds__(THREADS) void k_place(const int* __restrict__ ei,
    const float* __restrict__ ea, const int* __restrict__ rank,
    const int* __restrict__ rowptr, int2* __restrict__ epk){
  int e = blockIdx.x*THREADS + threadIdx.x;
  int d = ei[NE + e];
  int pos = rowptr[d] + rank[e];
  epk[pos] = make_int2(ei[e], __float_as_int(ea[e]));
}

// graph boundaries from sorted batch index
__global__ __launch_bounds__(THREADS) void k_gptr(const int* __restrict__ batch, int* __restrict__ gptr){
  int n = blockIdx.x*THREADS + threadIdx.x;
  int bc = batch[n];
  if (n == 0){ for (int g = 0; g <= bc; g++) gptr[g] = 0; }
  else {
    int pb = batch[n-1];
    if (pb != bc) for (int g = pb+1; g <= bc; g++) gptr[g] = n;
  }
  if (n == NN-1){ for (int g = bc+1; g <= NG; g++) gptr[g] = NN; }
}

// ---- GATConv node precompute: lane-per-channel, transposed weights ----
__global__ __launch_bounds__(THREADS) void k_att_node(const float* __restrict__ X,
    const float* __restrict__ wT, const float* __restrict__ a1, const float* __restrict__ a2,
    bf16* __restrict__ xt, float* __restrict__ s1, float* __restrict__ s2){
  int gid = blockIdx.x*THREADS + threadIdx.x;
  int n = gid >> 5, c = gid & 31;
  const float* xr = X + (size_t)n*32;
  float t = 0.f;
  #pragma unroll
  for (int k = 0; k < 32; k++) t += xr[k]*wT[k*32+c];
  xt[(size_t)n*32 + c] = f2b(t);                 // coalesced 2B/lane
  float p1 = redsum32(t*a1[c]);
  float p2 = a2 ? redsum32(t*a2[c]) : 0.f;
  if (c == 0){ s1[n] = p1; if (s2) s2[n] = p2; }
}

// ---- GRU via MFMA (unchanged) ----
__global__ __launch_bounds__(THREADS) void k_gru_mfma(const bf16* __restrict__ HV,
    float* __restrict__ S,
    const float* __restrict__ wih, const float* __restrict__ whh,
    const float* __restrict__ bih, const float* __restrict__ bhh){
  int wid  = (blockIdx.x*THREADS + threadIdx.x) >> 6;
  int lane = threadIdx.x & 63;
  int cl = lane & 15;
  int kb = lane >> 4;
  short8v BW[12];
  #pragma unroll
  for (int g = 0; g < 6; g++){
    const float* wr = wih + (size_t)(g*16 + cl)*32 + kb*8;
    const float* vr = whh + (size_t)(g*16 + cl)*32 + kb*8;
    short8v bw, bv;
    #pragma unroll
    for (int j = 0; j < 8; j++){ bw[j] = (short)bfbits(wr[j]); bv[j] = (short)bfbits(vr[j]); }
    BW[g] = bw; BW[6+g] = bv;
  }
  float bI[6], bH[6];
  #pragma unroll
  for (int g = 0; g < 6; g++){ bI[g] = bih[g*16 + cl]; bH[g] = bhh[g*16 + cl]; }

  #pragma unroll 2
  for (int t = 0; t < 8; t++){
    int nb = (wid*8 + t) * 16;
    short8v Ah = *(const short8v*)(HV + (size_t)(nb + cl)*32 + kb*8);
    const float* xr = S + (size_t)(nb + cl)*32 + kb*8;
    short8v Ax;
    #pragma unroll
    for (int j = 0; j < 8; j++) Ax[j] = (short)bfbits(xr[j]);
    f32x4 gi[6], gh[6];
    #pragma unroll
    for (int g = 0; g < 6; g++){
      f32x4 a, b;
      #pragma unroll
      for (int q = 0; q < 4; q++){ a[q] = bI[g]; b[q] = bH[g]; }
      gi[g] = __builtin_amdgcn_mfma_f32_16x16x32_bf16(Ah, BW[g],   a, 0, 0, 0);
      gh[g] = __builtin_amdgcn_mfma_f32_16x16x32_bf16(Ax, BW[6+g], b, 0, 0, 0);
    }
    #pragma unroll
    for (int r = 0; r < 4; r++){
      int node = nb + kb*4 + r;
      float* srow = S + (size_t)node*32;
      float x0 = srow[cl], x1 = srow[16 + cl];
      float r0 = sigm(gi[0][r] + gh[0][r]);
      float z0 = sigm(gi[2][r] + gh[2][r]);
      float n0 = tanhf(gi[4][r] + r0*gh[4][r]);
      float r1 = sigm(gi[1][r] + gh[1][r]);
      float z1 = sigm(gi[3][r] + gh[3][r]);
      float n1 = tanhf(gi[5][r] + r1*gh[5][r]);
      srow[cl]      = fmaxf((1.f - z0)*n0 + z0*x0, 0.f);
      srow[16 + cl] = fmaxf((1.f - z1)*n1 + z1*x1, 0.f);
    }
  }
}

// ---------------- edge-parallel logits (GATEConv only) ----------------
// raw score WITHOUT dst term / outer lrelu (added in k_conv). 4 lanes/edge. grid = NE/512.
__global__ __launch_bounds__(THREADS) void k_elog1(const int2* __restrict__ epk,
    const bf16* __restrict__ U,
    const float* __restrict__ w1 /*32x33*/, const float* __restrict__ attl,
    float* __restrict__ elog){
  int q  = threadIdx.x & 3;        // 16B chunk of the row (channels q*8..q*8+7)
  int lg = threadIdx.x >> 2;       // local group 0..63
  float wc[8], at[8];
  #pragma unroll
  for (int j = 0; j < 8; j++){
    wc[j] = w1[(q*8 + j)*33 + 32];
    at[j] = attl[q*8 + j];
  }
  int base = blockIdx.x * 512;
  #pragma unroll 2
  for (int i = 0; i < 8; i++){
    int p = base + i*64 + lg;
    int2 pk = epk[p];
    int si = pk.x;
    float a = __int_as_float(pk.y);
    short8v u8 = *(const short8v*)(U + (size_t)si*32 + q*8);
    float t = 0.f;
    #pragma unroll
    for (int j = 0; j < 8; j++) t += at[j]*lrelu(s2f(u8[j]) + a*wc[j]);
    t += __shfl_xor(t, 1, 4);
    t += __shfl_xor(t, 2, 4);
    if (q == 0) elog[p] = t;
  }
}

// ---- conv: logit = lrelu(score + term[node]); softmax + 8-way weighted row gather ----
__global__ __launch_bounds__(THREADS) void k_conv(const int* __restrict__ rowptr,
    const int2* __restrict__ epk, const float* __restrict__ lg,
    const float* __restrict__ alsrc, const float* __restrict__ term,
    const bf16* __restrict__ ROWS, const float* __restrict__ bias,
    bf16* __restrict__ HV){
  int node = blockIdx.x*(THREADS/32) + (threadIdx.x >> 5);
  int c32 = threadIdx.x & 31;
  int ws = rowptr[node], we = rowptr[node+1];
  float tv = term[node];
  // pass 1: online softmax, lane-parallel chunks of 32
  float m = -INFINITY, s = 0.f;
  for (int p0 = ws; p0 < we; p0 += 32){
    int p = p0 + c32;
    bool ok = p < we;
    float sc;
    if (lg) sc = ok ? lg[p] : 0.f;
    else    sc = ok ? alsrc[epk[p].x] : 0.f;
    float l = ok ? lrelu(sc + tv) : -INFINITY;
    float cm = redmax32(l);
    float mn = fmaxf(m, cm);
    float e = ok ? expf(l - mn) : 0.f;
    float cs = redsum32(e);
    s = s*expf(m - mn) + cs;
    m = mn;
  }
  float inv = 1.f/(s + 1e-16f);
  // pass 2: 8 edges x 4 chunks; lane = eg*4 + cb reads 16B of edge eg's row
  int eg = c32 >> 2, cb = c32 & 3;
  float acc[8];
  #pragma unroll
  for (int j = 0; j < 8; j++) acc[j] = 0.f;
  for (int p0 = ws; p0 < we; p0 += 8){
    int p = p0 + eg;
    bool ok = p < we;
    int pp = ok ? p : ws;
    int si = epk[pp].x;
    float sc = lg ? lg[pp] : alsrc[si];
    float w = ok ? expf(lrelu(sc + tv) - m) : 0.f;
    short8v r8 = *(const short8v*)(ROWS + (size_t)si*32 + cb*8);
    #pragma unroll
    for (int j = 0; j < 8; j++) acc[j] += s2f(r8[j]) * w;
  }
  #pragma unroll
  for (int j = 0; j < 8; j++){
    acc[j] += __shfl_xor(acc[j], 4, 32);
    acc[j] += __shfl_xor(acc[j], 8, 32);
    acc[j] += __shfl_xor(acc[j], 16, 32);
  }
  if (eg == 0){
    unsigned int o[4];
    #pragma unroll
    for (int j2 = 0; j2 < 4; j2++){
      float h0 = eluf(acc[2*j2  ]*inv + bias[cb*8 + 2*j2  ]);
      float h1 = eluf(acc[2*j2+1]*inv + bias[cb*8 + 2*j2+1]);
      o[j2] = pack2(h0, h1);
    }
    *(uint4*)(HV + (size_t)node*32 + cb*8) = make_uint4(o[0], o[1], o[2], o[3]);
  }
}

// ---------------- readout ----------------
__global__ __launch_bounds__(THREADS) void k_rsum(const int* __restrict__ gptr,
    const float* __restrict__ X, float* __restrict__ gout){
  int g = blockIdx.x*(THREADS/32) + (threadIdx.x >> 5);
  int c = threadIdx.x & 31;
  int gs = gptr[g], ge = gptr[g+1];
  float acc = 0.f;
  for (int n = gs; n < ge; n++) acc += X[(size_t)n*32 + c];
  gout[(size_t)g*32 + c] = fmaxf(acc, 0.f);
}

// one readout timestep: softmax over nodes of graph + weighted sum + GRU3
__global__ __launch_bounds__(THREADS) void k_rstep(const int* __restrict__ gptr,
    const float* __restrict__ anode, const bf16* __restrict__ XS,
    const float* __restrict__ q, const float* __restrict__ mbias,
    float* __restrict__ gout,
    const float* __restrict__ wih, const float* __restrict__ whh,
    const float* __restrict__ bih, const float* __restrict__ bhh){
  int g = blockIdx.x*(THREADS/32) + (threadIdx.x >> 5);
  int c = threadIdx.x & 31;
  float orow = gout[(size_t)g*32 + c];
  float ag = redsum32(orow * q[c]);
  int gs = gptr[g], ge = gptr[g+1];
  float m = -INFINITY, s = 0.f;
  for (int p0 = gs; p0 < ge; p0 += 32){
    int p = p0 + c;
    bool ok = p < ge;
    float lg = ok ? lrelu(anode[p] + ag) : -INFINITY;
    float cm = redmax32(lg);
    float mn = fmaxf(m, cm);
    float e = ok ? expf(lg - mn) : 0.f;
    float cs = redsum32(e);
    s = s*expf(m - mn) + cs;
    m = mn;
  }
  float inv = 1.f/(s + 1e-16f);
  float acc = 0.f;
  int n = gs;
  for (; n + 4 <= ge; n += 4){
    float e0 = expf(lrelu(anode[n]   + ag) - m);
    float e1 = expf(lrelu(anode[n+1] + ag) - m);
    float e2 = expf(lrelu(anode[n+2] + ag) - m);
    float e3 = expf(lrelu(anode[n+3] + ag) - m);
    acc += b2f(XS[(size_t)(n  )*32 + c])*e0 + b2f(XS[(size_t)(n+1)*32 + c])*e1
         + b2f(XS[(size_t)(n+2)*32 + c])*e2 + b2f(XS[(size_t)(n+3)*32 + c])*e3;
  }
  for (; n < ge; n++)
    acc += b2f(XS[(size_t)n*32 + c]) * expf(lrelu(anode[n] + ag) - m);
  acc *= inv;
  float hv = eluf(acc + mbias[c]);
  gout[(size_t)g*32 + c] = gru_relu(hv, orow, c, wih, whh, bih, bhh);
}

// y = mish(out @ lin2^T + b)
__global__ __launch_bounds__(THREADS) void k_final(const float* __restrict__ out32,
    const float* __restrict__ w /*64x32*/, const float* __restrict__ b,
    float* __restrict__ y){
  int gid = blockIdx.x*THREADS + threadIdx.x;
  int g = gid >> 6, oc = gid & 63;
  const float* orow = out32 + (size_t)g*32;
  const float* wr = w + oc*32;
  float acc = b[oc];
  #pragma unroll
  for (int k = 0; k < 32; k++) acc += orow[k]*wr[k];
  float sp = fmaxf(acc, 0.f) + log1pf(expf(-fabsf(acc)));
  y[(size_t)g*64 + oc] = acc * tanhf(sp);
}

extern "C" void kernel_launch(void* const* d_in, const int* in_sizes, int n_in,
                              void* d_out, int out_size, void* d_ws, size_t ws_size,
                              hipStream_t stream){
  const float* x_in     = (const float*)d_in[0];
  const float* ea       = (const float*)d_in[1];
  const int*   ei       = (const int*)  d_in[2];
  const int*   batch    = (const int*)  d_in[3];
  const float* lin1_w   = (const float*)d_in[4];
  const float* lin1_b   = (const float*)d_in[5];
  const float* g_lin1_w = (const float*)d_in[6];
  const float* g_lin2_w = (const float*)d_in[7];
  const float* g_att_l  = (const float*)d_in[8];
  const float* g_att_r  = (const float*)d_in[9];
  const float* g_bias   = (const float*)d_in[10];
  const float* gru1_wih = (const float*)d_in[11];
  const float* gru1_whh = (const float*)d_in[12];
  const float* gru1_bih = (const float*)d_in[13];
  const float* gru1_bhh = (const float*)d_in[14];
  const float* a_lin_w  = (const float*)d_in[15];
  const float* a_att_src= (const float*)d_in[16];
  const float* a_att_dst= (const float*)d_in[17];
  const float* a_bias   = (const float*)d_in[18];
  const float* gru2_wih = (const float*)d_in[19];
  const float* gru2_whh = (const float*)d_in[20];
  const float* gru2_bih = (const float*)d_in[21];
  const float* gru2_bhh = (const float*)d_in[22];
  const float* m_lin_w  = (const float*)d_in[23];
  const float* m_att_src= (const float*)d_in[24];
  const float* m_att_dst= (const float*)d_in[25];
  const float* m_bias   = (const float*)d_in[26];
  const float* gru3_wih = (const float*)d_in[27];
  const float* gru3_whh = (const float*)d_in[28];
  const float* gru3_bih = (const float*)d_in[29];
  const float* gru3_bhh = (const float*)d_in[30];
  const float* lin2_w   = (const float*)d_in[31];
  const float* lin2_b   = (const float*)d_in[32];

  float* W = (float*)d_ws;
  float* X     = W;                      // NN*32 f32
  bf16*  BA    = (bf16*)(W + 8388608);   // NN*32 bf16 : u / h1 / xt / xs
  bf16*  BB    = (bf16*)(W + 12582912);  // NN*32 bf16 : v / h2
  int2*  EPK   = (int2*) (W + 16777216); // NE x (src, ea-bits)
  float* ELOG  = W + 20971520;           // NE raw GATEConv edge scores
  int*   RANK  = (int*)  (W + 23068672); // NE within-dst ranks
  int*   ROWPTR= (int*)  (W + 25165824); // NN+1 (pad)
  int*   HIST  = (int*)  (W + 25428032); // NN
  int*   BTOT  = (int*)  (W + 25690176); // 1024
  float* NS1   = W + 25691200;           // NN : nr / al / a_node
  float* NS2   = W + 25953344;           // NN : ar
  int*   GPTR  = (int*)  (W + 26215488); // NG+1 (pad)
  float* GOUT  = W + 26223744;           // NG*32
  float* Q     = W + 26485888;           // 32
  float* LIN1T = W + 26485920;           // 54*32
  float* G1T   = W + 26487648;           // 1024
  float* G2T   = W + 26488672;           // 1024
  float* AT    = W + 26489696;           // 1024
  float* MT    = W + 26490720;           // 1024

  dim3 b(THREADS);
  const int gNode  = NN/THREADS;        // 1024
  const int gNodeC = (NN*32)/THREADS;   // 32768 : lane-per-channel node kernels
  const int gEdge  = NE/THREADS;        // 8192
  const int gElog1 = NE/512;            // 4096
  const int gNode32= NN/(THREADS/32);   // 32768 : node-per-32-lane (k_conv)
  const int gG32   = NG/(THREADS/32);   // 1024
  const int gGRU   = NN/(16*8*4);       // 512

  // weight transposes + q
  k_prep<<<1, 256, 0, stream>>>(lin1_w, g_lin1_w, g_lin2_w, a_lin_w, m_lin_w, m_att_dst,
      LIN1T, G1T, G2T, AT, MT, Q);

  // fused atom embedding + GATEConv node precompute (coalesced)
  k_embed<<<gNodeC, b, 0, stream>>>(x_in, LIN1T, lin1_b, G1T, G2T, g_att_r, X, BA, BB, NS1);

  // CSR build (dst-sorted; single atomic pass, atomic-free placement)
  k_filli<<<gNode, b, 0, stream>>>(HIST, 0, NN);
  k_histrank<<<gEdge, b, 0, stream>>>(ei, HIST, RANK);
  k_scan1<<<gNode, b, 0, stream>>>(HIST, ROWPTR, BTOT);
  k_scan2<<<1, 1024, 0, stream>>>(BTOT);
  k_scan3<<<gNode, b, 0, stream>>>(ROWPTR, BTOT);
  k_place<<<gEdge, b, 0, stream>>>(ei, ea, RANK, ROWPTR, EPK);
  k_gptr<<<gNode, b, 0, stream>>>(batch, GPTR);

  // GATEConv + GRU1  (conv writes h into BA, which is dead after k_elog1)
  k_elog1<<<gElog1, b, 0, stream>>>(EPK, BA, g_lin1_w, g_att_l, ELOG);
  k_conv<<<gNode32, b, 0, stream>>>(ROWPTR, EPK, ELOG, nullptr, NS1, BB, g_bias, BA);
  k_gru_mfma<<<gGRU, b, 0, stream>>>(BA, X, gru1_wih, gru1_whh, gru1_bih, gru1_bhh);

  // GATConv + GRU2  (conv gathers al[src] directly; writes h into BB)
  k_att_node<<<gNodeC, b, 0, stream>>>(X, AT, a_att_src, a_att_dst, BA, NS1, NS2);
  k_conv<<<gNode32, b, 0, stream>>>(ROWPTR, EPK, nullptr, NS1, NS2, BA, a_bias, BB);
  k_gru_mfma<<<gGRU, b, 0, stream>>>(BB, X, gru2_wih, gru2_whh, gru2_bih, gru2_bhh);

  // readout
  k_rsum<<<gG32, b, 0, stream>>>(GPTR, X, GOUT);
  k_att_node<<<gNodeC, b, 0, stream>>>(X, MT, m_att_src, nullptr, BA, NS1, nullptr);
  for (int t = 0; t < 2; t++){
    k_rstep<<<gG32, b, 0, stream>>>(GPTR, NS1, BA, Q, m_bias, GOUT,
        gru3_wih, gru3_whh, gru3_bih, gru3_bhh);
  }

  k_final<<<(NG*64)/THREADS, b, 0, stream>>>(GOUT, lin2_w, lin2_b, (float*)d_out);
}

// Round 12
// 616.422 us; speedup vs baseline: 1.3466x; 1.3466x over previous
//
#include <hip/hip_runtime.h>
#include <hip/hip_bf16.h>
#include <math.h>

#define NN 262144
#define NE 2097152
#define NG 8192
#define THREADS 256

typedef __hip_bfloat16 bf16;
typedef __attribute__((ext_vector_type(8))) short short8v;   // 8 bf16 (4 VGPRs)
typedef __attribute__((ext_vector_type(4))) float f32x4;

static __device__ __forceinline__ float lrelu(float x){ return x > 0.f ? x : 0.01f*x; }
static __device__ __forceinline__ float eluf(float x){ return x > 0.f ? x : expm1f(x); }
static __device__ __forceinline__ float sigm(float x){ return 1.f/(1.f+expf(-x)); }
static __device__ __forceinline__ float b2f(bf16 v){ return __bfloat162float(v); }
static __device__ __forceinline__ bf16 f2b(float v){ return __float2bfloat16(v); }
// bit-reinterpret a raw bf16 (held in a short) to float — NEVER value-convert!
static __device__ __forceinline__ float s2f(short s){
  return __uint_as_float(((unsigned int)(unsigned short)s) << 16);
}

static __device__ __forceinline__ unsigned short bfbits(float f){
  union { bf16 b; unsigned short s; } u; u.b = f2b(f); return u.s;
}
static __device__ __forceinline__ unsigned int pack2(float lo, float hi){
  return (unsigned int)bfbits(lo) | ((unsigned int)bfbits(hi) << 16);
}

static __device__ __forceinline__ float redsum32(float t){
  #pragma unroll
  for (int o = 16; o > 0; o >>= 1) t += __shfl_xor(t, o, 32);
  return t;
}
static __device__ __forceinline__ float redmax32(float t){
  #pragma unroll
  for (int o = 16; o > 0; o >>= 1) t = fmaxf(t, __shfl_xor(t, o, 32));
  return t;
}

// GRU fused helper for the tiny readout kernel (32 lanes = one row)
static __device__ __forceinline__ float gru_relu(float hv, float xv, int c,
    const float* __restrict__ wih, const float* __restrict__ whh,
    const float* __restrict__ bih, const float* __restrict__ bhh){
  float gr = bih[c], gz = bih[32+c], gn = bih[64+c];
  float hr = bhh[c], hz = bhh[32+c], hn = bhh[64+c];
  #pragma unroll 8
  for (int k = 0; k < 32; k++){
    float hk = __shfl(hv, k, 32);
    float xk = __shfl(xv, k, 32);
    gr += hk*wih[(     c)*32 + k];
    gz += hk*wih[(32 + c)*32 + k];
    gn += hk*wih[(64 + c)*32 + k];
    hr += xk*whh[(     c)*32 + k];
    hz += xk*whh[(32 + c)*32 + k];
    hn += xk*whh[(64 + c)*32 + k];
  }
  float r = sigm(gr + hr), z = sigm(gz + hz);
  float nn2 = tanhf(gn + r*hn);
  return fmaxf((1.f - z)*nn2 + z*xv, 0.f);
}

__global__ __launch_bounds__(THREADS) void k_filli(int* __restrict__ p, int v, int n){
  int i = blockIdx.x*THREADS + threadIdx.x;
  if (i < n) p[i] = v;
}

// ---- fused atom embedding + GATEConv node precompute, via MFMA ----
// One wave = 8 tiles of 16 nodes (mirrors k_gru_mfma layout, HW-verified there).
// lin1: D = xin(bf16) @ lin1_w^T + b, K=54 padded to 64 (2 chunks); lrelu.
// u/v: o (via LDS transpose) @ w1/w2^T.  nr = o . attr_r (width-16 reduce).
__global__ __launch_bounds__(THREADS) void k_embed(const float* __restrict__ xin,
    const float* __restrict__ lw /*32x54*/, const float* __restrict__ lb,
    const float* __restrict__ w1 /*32x33*/, const float* __restrict__ w2 /*32x32*/,
    const float* __restrict__ attr_r, float* __restrict__ X,
    bf16* __restrict__ u, bf16* __restrict__ v, float* __restrict__ nr){
  __shared__ float ol[4][16][33];
  int wid  = (blockIdx.x*THREADS + threadIdx.x) >> 6;
  int wv   = threadIdx.x >> 6;
  int lane = threadIdx.x & 63;
  int cl = lane & 15;
  int kb = lane >> 4;
  // B-frags: lin1 (2 col-groups x 2 K-chunks), u, v (2 col-groups each)
  short8v BL[2][2], BU[2], BV[2];
  #pragma unroll
  for (int g = 0; g < 2; g++){
    #pragma unroll
    for (int kc = 0; kc < 2; kc++){
      short8v t;
      #pragma unroll
      for (int j = 0; j < 8; j++){
        int k = kc*32 + kb*8 + j;
        t[j] = (k < 54) ? (short)bfbits(lw[(size_t)(g*16+cl)*54 + k]) : (short)0;
      }
      BL[g][kc] = t;
    }
    short8v tu, tv;
    #pragma unroll
    for (int j = 0; j < 8; j++){
      tu[j] = (short)bfbits(w1[(size_t)(g*16+cl)*33 + kb*8 + j]);
      tv[j] = (short)bfbits(w2[(size_t)(g*16+cl)*32 + kb*8 + j]);
    }
    BU[g] = tu; BV[g] = tv;
  }
  float bb0 = lb[cl], bb1 = lb[16+cl];
  float ar0 = attr_r[cl], ar1 = attr_r[16+cl];
  f32x4 zero; zero[0]=0.f; zero[1]=0.f; zero[2]=0.f; zero[3]=0.f;

  for (int t = 0; t < 8; t++){
    int nb = (wid*8 + t)*16;
    const float* xrow = xin + (size_t)(nb + cl)*54;
    // A chunk 0: k = kb*8+j (<32, all valid); 8B-aligned float2 loads
    short8v Ax0, Ax1;
    const float2* x2 = (const float2*)(xrow + kb*8);
    #pragma unroll
    for (int jj = 0; jj < 4; jj++){
      float2 tvv = x2[jj];
      Ax0[2*jj]   = (short)bfbits(tvv.x);
      Ax0[2*jj+1] = (short)bfbits(tvv.y);
    }
    // A chunk 1: k = 32+kb*8+j, pad k>=54 with 0
    #pragma unroll
    for (int j = 0; j < 8; j++){
      int k = 32 + kb*8 + j;
      Ax1[j] = (k < 54) ? (short)bfbits(xrow[k]) : (short)0;
    }
    f32x4 a0, a1;
    #pragma unroll
    for (int q = 0; q < 4; q++){ a0[q] = bb0; a1[q] = bb1; }
    f32x4 d0 = __builtin_amdgcn_mfma_f32_16x16x32_bf16(Ax0, BL[0][0], a0, 0, 0, 0);
    d0 = __builtin_amdgcn_mfma_f32_16x16x32_bf16(Ax1, BL[0][1], d0, 0, 0, 0);
    f32x4 d1 = __builtin_amdgcn_mfma_f32_16x16x32_bf16(Ax0, BL[1][0], a1, 0, 0, 0);
    d1 = __builtin_amdgcn_mfma_f32_16x16x32_bf16(Ax1, BL[1][1], d1, 0, 0, 0);
    #pragma unroll
    for (int r = 0; r < 4; r++){ d0[r] = lrelu(d0[r]); d1[r] = lrelu(d1[r]); }
    // store X (full-line pattern proven in gru_mfma) + stage to LDS for transpose
    #pragma unroll
    for (int r = 0; r < 4; r++){
      int node = nb + kb*4 + r;
      float* srow = X + (size_t)node*32;
      srow[cl]      = d0[r];
      srow[16 + cl] = d1[r];
      ol[wv][kb*4 + r][cl]      = d0[r];
      ol[wv][kb*4 + r][16 + cl] = d1[r];
    }
    // nr = o . attr_r  (reduce over cl within each 16-lane group)
    #pragma unroll
    for (int r = 0; r < 4; r++){
      float vsum = d0[r]*ar0 + d1[r]*ar1;
      vsum += __shfl_xor(vsum, 1, 16);
      vsum += __shfl_xor(vsum, 2, 16);
      vsum += __shfl_xor(vsum, 4, 16);
      vsum += __shfl_xor(vsum, 8, 16);
      if (cl == 0) nr[nb + kb*4 + r] = vsum;
    }
    __syncthreads();
    // A-frag for o: A[m=cl][k=kb*8+j] from LDS
    short8v Ao;
    #pragma unroll
    for (int j = 0; j < 8; j++) Ao[j] = (short)bfbits(ol[wv][cl][kb*8 + j]);
    f32x4 u0 = __builtin_amdgcn_mfma_f32_16x16x32_bf16(Ao, BU[0], zero, 0, 0, 0);
    f32x4 u1 = __builtin_amdgcn_mfma_f32_16x16x32_bf16(Ao, BU[1], zero, 0, 0, 0);
    f32x4 v0 = __builtin_amdgcn_mfma_f32_16x16x32_bf16(Ao, BV[0], zero, 0, 0, 0);
    f32x4 v1 = __builtin_amdgcn_mfma_f32_16x16x32_bf16(Ao, BV[1], zero, 0, 0, 0);
    #pragma unroll
    for (int r = 0; r < 4; r++){
      int node = nb + kb*4 + r;
      bf16* ur = u + (size_t)node*32;
      bf16* vr = v + (size_t)node*32;
      ur[cl]      = f2b(u0[r]);
      ur[16 + cl] = f2b(u1[r]);
      vr[cl]      = f2b(v0[r]);
      vr[16 + cl] = f2b(v1[r]);
    }
    __syncthreads();
  }
}

// ---------------- CSR build ----------------
// histogram + within-dst rank in ONE atomic pass
__global__ __launch_bounds__(THREADS) void k_histrank(const int* __restrict__ ei,
    int* __restrict__ hist, int* __restrict__ rank){
  int e = blockIdx.x*THREADS + threadIdx.x;
  rank[e] = atomicAdd(hist + ei[NE + e], 1);
}

__global__ __launch_bounds__(THREADS) void k_scan1(const int* __restrict__ hist,
    int* __restrict__ rowptr, int* __restrict__ btot){
  __shared__ int sh[THREADS];
  int i = blockIdx.x*THREADS + threadIdx.x;
  int v = hist[i];
  sh[threadIdx.x] = v; __syncthreads();
  #pragma unroll
  for (int off = 1; off < THREADS; off <<= 1){
    int t = (threadIdx.x >= off) ? sh[threadIdx.x - off] : 0;
    __syncthreads(); sh[threadIdx.x] += t; __syncthreads();
  }
  rowptr[i] = sh[threadIdx.x] - v;
  if (threadIdx.x == THREADS-1) btot[blockIdx.x] = sh[THREADS-1];
}

__global__ __launch_bounds__(1024) void k_scan2(int* __restrict__ btot){
  __shared__ int sh[1024];
  int i = threadIdx.x;
  int v = btot[i];
  sh[i] = v; __syncthreads();
  for (int off = 1; off < 1024; off <<= 1){
    int t = (i >= off) ? sh[i - off] : 0;
    __syncthreads(); sh[i] += t; __syncthreads();
  }
  btot[i] = sh[i] - v;  // exclusive
}

__global__ __launch_bounds__(THREADS) void k_scan3(int* __restrict__ rowptr,
    const int* __restrict__ btot){
  int i = blockIdx.x*THREADS + threadIdx.x;
  rowptr[i] = rowptr[i] + btot[i >> 8];
  if (i == 0) rowptr[NN] = NE;
}

// ATOMIC-FREE placement: pos = rowptr[dst] + rank[e]; single 8B scattered store
__global__ __launch_bounds__(THREADS) void k_place(const int* __restrict__ ei,
    const float* __restrict__ ea, const int* __restrict__ rank,
    const int* __restrict__ rowptr, int2* __restrict__ epk){
  int e = blockIdx.x*THREADS + threadIdx.x;
  int d = ei[NE + e];
  int pos = rowptr[d] + rank[e];
  epk[pos] = make_int2(ei[e], __float_as_int(ea[e]));
}

// graph boundaries from sorted batch index
__global__ __launch_bounds__(THREADS) void k_gptr(const int* __restrict__ batch, int* __restrict__ gptr){
  int n = blockIdx.x*THREADS + threadIdx.x;
  int bc = batch[n];
  if (n == 0){ for (int g = 0; g <= bc; g++) gptr[g] = 0; }
  else {
    int pb = batch[n-1];
    if (pb != bc) for (int g = pb+1; g <= bc; g++) gptr[g] = n;
  }
  if (n == NN-1){ for (int g = bc+1; g <= NG; g++) gptr[g] = NN; }
}

// ---- GATConv node precompute: one THREAD per node (round-10 proven form) ----
__global__ __launch_bounds__(THREADS) void k_att_node(const float* __restrict__ X,
    const float* __restrict__ w, const float* __restrict__ a1, const float* __restrict__ a2,
    bf16* __restrict__ xt, float* __restrict__ s1, float* __restrict__ s2){
  int n = blockIdx.x*THREADS + threadIdx.x;
  float x[32];
  const float* xr = X + (size_t)n*32;
  #pragma unroll
  for (int k = 0; k < 32; k++) x[k] = xr[k];
  unsigned int* t2 = (unsigned int*)(xt + (size_t)n*32);
  float p1 = 0.f, p2 = 0.f;
  #pragma unroll 2
  for (int c2 = 0; c2 < 16; c2++){
    float t0=0.f, t1=0.f;
    #pragma unroll
    for (int k = 0; k < 32; k++){
      float xv = x[k];
      t0 += xv * w[(2*c2  )*32 + k];
      t1 += xv * w[(2*c2+1)*32 + k];
    }
    p1 += t0*a1[2*c2] + t1*a1[2*c2+1];
    if (a2) p2 += t0*a2[2*c2] + t1*a2[2*c2+1];
    t2[c2] = pack2(t0, t1);
  }
  s1[n] = p1;
  if (s2) s2[n] = p2;
}

// ---- GRU via MFMA (unchanged) ----
__global__ __launch_bounds__(THREADS) void k_gru_mfma(const bf16* __restrict__ HV,
    float* __restrict__ S,
    const float* __restrict__ wih, const float* __restrict__ whh,
    const float* __restrict__ bih, const float* __restrict__ bhh){
  int wid  = (blockIdx.x*THREADS + threadIdx.x) >> 6;
  int lane = threadIdx.x & 63;
  int cl = lane & 15;
  int kb = lane >> 4;
  short8v BW[12];
  #pragma unroll
  for (int g = 0; g < 6; g++){
    const float* wr = wih + (size_t)(g*16 + cl)*32 + kb*8;
    const float* vr = whh + (size_t)(g*16 + cl)*32 + kb*8;
    short8v bw, bv;
    #pragma unroll
    for (int j = 0; j < 8; j++){ bw[j] = (short)bfbits(wr[j]); bv[j] = (short)bfbits(vr[j]); }
    BW[g] = bw; BW[6+g] = bv;
  }
  float bI[6], bH[6];
  #pragma unroll
  for (int g = 0; g < 6; g++){ bI[g] = bih[g*16 + cl]; bH[g] = bhh[g*16 + cl]; }

  #pragma unroll 2
  for (int t = 0; t < 8; t++){
    int nb = (wid*8 + t) * 16;
    short8v Ah = *(const short8v*)(HV + (size_t)(nb + cl)*32 + kb*8);
    const float* xr = S + (size_t)(nb + cl)*32 + kb*8;
    short8v Ax;
    #pragma unroll
    for (int j = 0; j < 8; j++) Ax[j] = (short)bfbits(xr[j]);
    f32x4 gi[6], gh[6];
    #pragma unroll
    for (int g = 0; g < 6; g++){
      f32x4 a, b;
      #pragma unroll
      for (int q = 0; q < 4; q++){ a[q] = bI[g]; b[q] = bH[g]; }
      gi[g] = __builtin_amdgcn_mfma_f32_16x16x32_bf16(Ah, BW[g],   a, 0, 0, 0);
      gh[g] = __builtin_amdgcn_mfma_f32_16x16x32_bf16(Ax, BW[6+g], b, 0, 0, 0);
    }
    #pragma unroll
    for (int r = 0; r < 4; r++){
      int node = nb + kb*4 + r;
      float* srow = S + (size_t)node*32;
      float x0 = srow[cl], x1 = srow[16 + cl];
      float r0 = sigm(gi[0][r] + gh[0][r]);
      float z0 = sigm(gi[2][r] + gh[2][r]);
      float n0 = tanhf(gi[4][r] + r0*gh[4][r]);
      float r1 = sigm(gi[1][r] + gh[1][r]);
      float z1 = sigm(gi[3][r] + gh[3][r]);
      float n1 = tanhf(gi[5][r] + r1*gh[5][r]);
      srow[cl]      = fmaxf((1.f - z0)*n0 + z0*x0, 0.f);
      srow[16 + cl] = fmaxf((1.f - z1)*n1 + z1*x1, 0.f);
    }
  }
}

// ---------------- edge-parallel logits (GATEConv only) ----------------
// raw score WITHOUT dst term / outer lrelu (added in k_conv). 4 lanes/edge. grid = NE/512.
__global__ __launch_bounds__(THREADS) void k_elog1(const int2* __restrict__ epk,
    const bf16* __restrict__ U,
    const float* __restrict__ w1 /*32x33*/, const float* __restrict__ attl,
    float* __restrict__ elog){
  int q  = threadIdx.x & 3;        // 16B chunk of the row (channels q*8..q*8+7)
  int lg = threadIdx.x >> 2;       // local group 0..63
  float wc[8], at[8];
  #pragma unroll
  for (int j = 0; j < 8; j++){
    wc[j] = w1[(q*8 + j)*33 + 32];
    at[j] = attl[q*8 + j];
  }
  int base = blockIdx.x * 512;
  #pragma unroll 2
  for (int i = 0; i < 8; i++){
    int p = base + i*64 + lg;
    int2 pk = epk[p];
    int si = pk.x;
    float a = __int_as_float(pk.y);
    short8v u8 = *(const short8v*)(U + (size_t)si*32 + q*8);
    float t = 0.f;
    #pragma unroll
    for (int j = 0; j < 8; j++) t += at[j]*lrelu(s2f(u8[j]) + a*wc[j]);
    t += __shfl_xor(t, 1, 4);
    t += __shfl_xor(t, 2, 4);
    if (q == 0) elog[p] = t;
  }
}

// ---- conv: logit = lrelu(score + term[node]); softmax + 8-way weighted row gather ----
__global__ __launch_bounds__(THREADS) void k_conv(const int* __restrict__ rowptr,
    const int2* __restrict__ epk, const float* __restrict__ lg,
    const float* __restrict__ alsrc, const float* __restrict__ term,
    const bf16* __restrict__ ROWS, const float* __restrict__ bias,
    bf16* __restrict__ HV){
  int node = blockIdx.x*(THREADS/32) + (threadIdx.x >> 5);
  int c32 = threadIdx.x & 31;
  int ws = rowptr[node], we = rowptr[node+1];
  float tv = term[node];
  // pass 1: online softmax, lane-parallel chunks of 32
  float m = -INFINITY, s = 0.f;
  for (int p0 = ws; p0 < we; p0 += 32){
    int p = p0 + c32;
    bool ok = p < we;
    float sc;
    if (lg) sc = ok ? lg[p] : 0.f;
    else    sc = ok ? alsrc[epk[p].x] : 0.f;
    float l = ok ? lrelu(sc + tv) : -INFINITY;
    float cm = redmax32(l);
    float mn = fmaxf(m, cm);
    float e = ok ? expf(l - mn) : 0.f;
    float cs = redsum32(e);
    s = s*expf(m - mn) + cs;
    m = mn;
  }
  float inv = 1.f/(s + 1e-16f);
  // pass 2: 8 edges x 4 chunks; lane = eg*4 + cb reads 16B of edge eg's row
  int eg = c32 >> 2, cb = c32 & 3;
  float acc[8];
  #pragma unroll
  for (int j = 0; j < 8; j++) acc[j] = 0.f;
  for (int p0 = ws; p0 < we; p0 += 8){
    int p = p0 + eg;
    bool ok = p < we;
    int pp = ok ? p : ws;
    int si = epk[pp].x;
    float sc = lg ? lg[pp] : alsrc[si];
    float w = ok ? expf(lrelu(sc + tv) - m) : 0.f;
    short8v r8 = *(const short8v*)(ROWS + (size_t)si*32 + cb*8);
    #pragma unroll
    for (int j = 0; j < 8; j++) acc[j] += s2f(r8[j]) * w;
  }
  #pragma unroll
  for (int j = 0; j < 8; j++){
    acc[j] += __shfl_xor(acc[j], 4, 32);
    acc[j] += __shfl_xor(acc[j], 8, 32);
    acc[j] += __shfl_xor(acc[j], 16, 32);
  }
  if (eg == 0){
    unsigned int o[4];
    #pragma unroll
    for (int j2 = 0; j2 < 4; j2++){
      float h0 = eluf(acc[2*j2  ]*inv + bias[cb*8 + 2*j2  ]);
      float h1 = eluf(acc[2*j2+1]*inv + bias[cb*8 + 2*j2+1]);
      o[j2] = pack2(h0, h1);
    }
    *(uint4*)(HV + (size_t)node*32 + cb*8) = make_uint4(o[0], o[1], o[2], o[3]);
  }
}

// ---------------- readout ----------------
__global__ __launch_bounds__(THREADS) void k_rsum(const int* __restrict__ gptr,
    const float* __restrict__ X, float* __restrict__ gout){
  int g = blockIdx.x*(THREADS/32) + (threadIdx.x >> 5);
  int c = threadIdx.x & 31;
  int gs = gptr[g], ge = gptr[g+1];
  float acc = 0.f;
  for (int n = gs; n < ge; n++) acc += X[(size_t)n*32 + c];
  gout[(size_t)g*32 + c] = fmaxf(acc, 0.f);
}

// q[k] = sum_c att_dst[c] * W[c][k]
__global__ void k_q(const float* __restrict__ w, const float* __restrict__ attd,
                    float* __restrict__ q){
  int k = threadIdx.x;
  float acc = 0.f;
  #pragma unroll
  for (int c = 0; c < 32; c++) acc += attd[c] * w[c*32 + k];
  q[k] = acc;
}

// one readout timestep: softmax over nodes of graph + weighted sum + GRU3
__global__ __launch_bounds__(THREADS) void k_rstep(const int* __restrict__ gptr,
    const float* __restrict__ anode, const bf16* __restrict__ XS,
    const float* __restrict__ q, const float* __restrict__ mbias,
    float* __restrict__ gout,
    const float* __restrict__ wih, const float* __restrict__ whh,
    const float* __restrict__ bih, const float* __restrict__ bhh){
  int g = blockIdx.x*(THREADS/32) + (threadIdx.x >> 5);
  int c = threadIdx.x & 31;
  float orow = gout[(size_t)g*32 + c];
  float ag = redsum32(orow * q[c]);
  int gs = gptr[g], ge = gptr[g+1];
  float m = -INFINITY, s = 0.f;
  for (int p0 = gs; p0 < ge; p0 += 32){
    int p = p0 + c;
    bool ok = p < ge;
    float lg = ok ? lrelu(anode[p] + ag) : -INFINITY;
    float cm = redmax32(lg);
    float mn = fmaxf(m, cm);
    float e = ok ? expf(lg - mn) : 0.f;
    float cs = redsum32(e);
    s = s*expf(m - mn) + cs;
    m = mn;
  }
  float inv = 1.f/(s + 1e-16f);
  float acc = 0.f;
  int n = gs;
  for (; n + 4 <= ge; n += 4){
    float e0 = expf(lrelu(anode[n]   + ag) - m);
    float e1 = expf(lrelu(anode[n+1] + ag) - m);
    float e2 = expf(lrelu(anode[n+2] + ag) - m);
    float e3 = expf(lrelu(anode[n+3] + ag) - m);
    acc += b2f(XS[(size_t)(n  )*32 + c])*e0 + b2f(XS[(size_t)(n+1)*32 + c])*e1
         + b2f(XS[(size_t)(n+2)*32 + c])*e2 + b2f(XS[(size_t)(n+3)*32 + c])*e3;
  }
  for (; n < ge; n++)
    acc += b2f(XS[(size_t)n*32 + c]) * expf(lrelu(anode[n] + ag) - m);
  acc *= inv;
  float hv = eluf(acc + mbias[c]);
  gout[(size_t)g*32 + c] = gru_relu(hv, orow, c, wih, whh, bih, bhh);
}

// y = mish(out @ lin2^T + b)
__global__ __launch_bounds__(THREADS) void k_final(const float* __restrict__ out32,
    const float* __restrict__ w /*64x32*/, const float* __restrict__ b,
    float* __restrict__ y){
  int gid = blockIdx.x*THREADS + threadIdx.x;
  int g = gid >> 6, oc = gid & 63;
  const float* orow = out32 + (size_t)g*32;
  const float* wr = w + oc*32;
  float acc = b[oc];
  #pragma unroll
  for (int k = 0; k < 32; k++) acc += orow[k]*wr[k];
  float sp = fmaxf(acc, 0.f) + log1pf(expf(-fabsf(acc)));
  y[(size_t)g*64 + oc] = acc * tanhf(sp);
}

extern "C" void kernel_launch(void* const* d_in, const int* in_sizes, int n_in,
                              void* d_out, int out_size, void* d_ws, size_t ws_size,
                              hipStream_t stream){
  const float* x_in     = (const float*)d_in[0];
  const float* ea       = (const float*)d_in[1];
  const int*   ei       = (const int*)  d_in[2];
  const int*   batch    = (const int*)  d_in[3];
  const float* lin1_w   = (const float*)d_in[4];
  const float* lin1_b   = (const float*)d_in[5];
  const float* g_lin1_w = (const float*)d_in[6];
  const float* g_lin2_w = (const float*)d_in[7];
  const float* g_att_l  = (const float*)d_in[8];
  const float* g_att_r  = (const float*)d_in[9];
  const float* g_bias   = (const float*)d_in[10];
  const float* gru1_wih = (const float*)d_in[11];
  const float* gru1_whh = (const float*)d_in[12];
  const float* gru1_bih = (const float*)d_in[13];
  const float* gru1_bhh = (const float*)d_in[14];
  const float* a_lin_w  = (const float*)d_in[15];
  const float* a_att_src= (const float*)d_in[16];
  const float* a_att_dst= (const float*)d_in[17];
  const float* a_bias   = (const float*)d_in[18];
  const float* gru2_wih = (const float*)d_in[19];
  const float* gru2_whh = (const float*)d_in[20];
  const float* gru2_bih = (const float*)d_in[21];
  const float* gru2_bhh = (const float*)d_in[22];
  const float* m_lin_w  = (const float*)d_in[23];
  const float* m_att_src= (const float*)d_in[24];
  const float* m_att_dst= (const float*)d_in[25];
  const float* m_bias   = (const float*)d_in[26];
  const float* gru3_wih = (const float*)d_in[27];
  const float* gru3_whh = (const float*)d_in[28];
  const float* gru3_bih = (const float*)d_in[29];
  const float* gru3_bhh = (const float*)d_in[30];
  const float* lin2_w   = (const float*)d_in[31];
  const float* lin2_b   = (const float*)d_in[32];

  float* W = (float*)d_ws;
  float* X     = W;                      // NN*32 f32
  bf16*  BA    = (bf16*)(W + 8388608);   // NN*32 bf16 : u / h1 / xt / xs
  bf16*  BB    = (bf16*)(W + 12582912);  // NN*32 bf16 : v / h2
  int2*  EPK   = (int2*) (W + 16777216); // NE x (src, ea-bits)
  float* ELOG  = W + 20971520;           // NE raw GATEConv edge scores
  int*   RANK  = (int*)  (W + 23068672); // NE within-dst ranks
  int*   ROWPTR= (int*)  (W + 25165824); // NN+1 (pad)
  int*   HIST  = (int*)  (W + 25428032); // NN
  int*   BTOT  = (int*)  (W + 25690176); // 1024
  float* NS1   = W + 25691200;           // NN : nr / al / a_node
  float* NS2   = W + 25953344;           // NN : ar
  int*   GPTR  = (int*)  (W + 26215488); // NG+1 (pad)
  float* GOUT  = W + 26223744;           // NG*32
  float* Q     = W + 26485888;           // 32

  dim3 b(THREADS);
  const int gNode  = NN/THREADS;        // 1024
  const int gEdge  = NE/THREADS;        // 8192
  const int gElog1 = NE/512;            // 4096
  const int gNode32= NN/(THREADS/32);   // 32768 : node-per-32-lane (k_conv)
  const int gG32   = NG/(THREADS/32);   // 1024
  const int gMFMA  = NN/(16*8*4);       // 512 : 4 waves/block, 8 tiles of 16 nodes/wave

  // fused atom embedding + GATEConv node precompute (MFMA)
  k_embed<<<gMFMA, b, 0, stream>>>(x_in, lin1_w, lin1_b, g_lin1_w, g_lin2_w, g_att_r,
      X, BA, BB, NS1);

  // CSR build (dst-sorted; single atomic pass, atomic-free placement)
  k_filli<<<gNode, b, 0, stream>>>(HIST, 0, NN);
  k_histrank<<<gEdge, b, 0, stream>>>(ei, HIST, RANK);
  k_scan1<<<gNode, b, 0, stream>>>(HIST, ROWPTR, BTOT);
  k_scan2<<<1, 1024, 0, stream>>>(BTOT);
  k_scan3<<<gNode, b, 0, stream>>>(ROWPTR, BTOT);
  k_place<<<gEdge, b, 0, stream>>>(ei, ea, RANK, ROWPTR, EPK);
  k_gptr<<<gNode, b, 0, stream>>>(batch, GPTR);

  // GATEConv + GRU1  (conv writes h into BA, which is dead after k_elog1)
  k_elog1<<<gElog1, b, 0, stream>>>(EPK, BA, g_lin1_w, g_att_l, ELOG);
  k_conv<<<gNode32, b, 0, stream>>>(ROWPTR, EPK, ELOG, nullptr, NS1, BB, g_bias, BA);
  k_gru_mfma<<<gMFMA, b, 0, stream>>>(BA, X, gru1_wih, gru1_whh, gru1_bih, gru1_bhh);

  // GATConv + GRU2  (conv gathers al[src] directly; writes h into BB)
  k_att_node<<<gNode, b, 0, stream>>>(X, a_lin_w, a_att_src, a_att_dst, BA, NS1, NS2);
  k_conv<<<gNode32, b, 0, stream>>>(ROWPTR, EPK, nullptr, NS1, NS2, BA, a_bias, BB);
  k_gru_mfma<<<gMFMA, b, 0, stream>>>(BB, X, gru2_wih, gru2_whh, gru2_bih, gru2_bhh);

  // readout
  k_rsum<<<gG32, b, 0, stream>>>(GPTR, X, GOUT);
  k_att_node<<<gNode, b, 0, stream>>>(X, m_lin_w, m_att_src, nullptr, BA, NS1, nullptr);
  k_q<<<1, 32, 0, stream>>>(m_lin_w, m_att_dst, Q);
  for (int t = 0; t < 2; t++){
    k_rstep<<<gG32, b, 0, stream>>>(GPTR, NS1, BA, Q, m_bias, GOUT,
        gru3_wih, gru3_whh, gru3_bih, gru3_bhh);
  }

  k_final<<<(NG*64)/THREADS, b, 0, stream>>>(GOUT, lin2_w, lin2_b, (float*)d_out);
}

// Round 13
// 535.772 us; speedup vs baseline: 1.5493x; 1.1505x over previous
//
#include <hip/hip_runtime.h>
#include <hip/hip_bf16.h>
#include <math.h>

#define NN 262144
#define NE 2097152
#define NG 8192
#define THREADS 256

typedef __hip_bfloat16 bf16;
typedef __attribute__((ext_vector_type(8))) short short8v;   // 8 bf16 (4 VGPRs)
typedef __attribute__((ext_vector_type(4))) float f32x4;

static __device__ __forceinline__ float lrelu(float x){ return x > 0.f ? x : 0.01f*x; }
// fast transcendentals: hardware v_exp_f32-based (≈1ulp; bf16 storage dominates error)
static __device__ __forceinline__ float eluf(float x){ return x > 0.f ? x : __expf(x) - 1.f; }
static __device__ __forceinline__ float sigm(float x){ return 1.f/(1.f + __expf(-x)); }
static __device__ __forceinline__ float tanh_fast(float x){
  float e = __expf(2.f*x); return 1.f - 2.f/(e + 1.f);
}
static __device__ __forceinline__ float b2f(bf16 v){ return __bfloat162float(v); }
static __device__ __forceinline__ bf16 f2b(float v){ return __float2bfloat16(v); }
// bit-reinterpret a raw bf16 (held in a short) to float — NEVER value-convert!
static __device__ __forceinline__ float s2f(short s){
  return __uint_as_float(((unsigned int)(unsigned short)s) << 16);
}

static __device__ __forceinline__ unsigned short bfbits(float f){
  union { bf16 b; unsigned short s; } u; u.b = f2b(f); return u.s;
}
static __device__ __forceinline__ unsigned int pack2(float lo, float hi){
  return (unsigned int)bfbits(lo) | ((unsigned int)bfbits(hi) << 16);
}

static __device__ __forceinline__ float redsum32(float t){
  #pragma unroll
  for (int o = 16; o > 0; o >>= 1) t += __shfl_xor(t, o, 32);
  return t;
}
static __device__ __forceinline__ float redmax32(float t){
  #pragma unroll
  for (int o = 16; o > 0; o >>= 1) t = fmaxf(t, __shfl_xor(t, o, 32));
  return t;
}

// GRU fused helper for the tiny readout kernel (32 lanes = one row)
static __device__ __forceinline__ float gru_relu(float hv, float xv, int c,
    const float* __restrict__ wih, const float* __restrict__ whh,
    const float* __restrict__ bih, const float* __restrict__ bhh){
  float gr = bih[c], gz = bih[32+c], gn = bih[64+c];
  float hr = bhh[c], hz = bhh[32+c], hn = bhh[64+c];
  #pragma unroll 8
  for (int k = 0; k < 32; k++){
    float hk = __shfl(hv, k, 32);
    float xk = __shfl(xv, k, 32);
    gr += hk*wih[(     c)*32 + k];
    gz += hk*wih[(32 + c)*32 + k];
    gn += hk*wih[(64 + c)*32 + k];
    hr += xk*whh[(     c)*32 + k];
    hz += xk*whh[(32 + c)*32 + k];
    hn += xk*whh[(64 + c)*32 + k];
  }
  float r = sigm(gr + hr), z = sigm(gz + hz);
  float nn2 = tanh_fast(gn + r*hn);
  return fmaxf((1.f - z)*nn2 + z*xv, 0.f);
}

__global__ __launch_bounds__(THREADS) void k_filli(int* __restrict__ p, int v, int n){
  int i = blockIdx.x*THREADS + threadIdx.x;
  if (i < n) p[i] = v;
}

// ---- fused atom embedding + GATEConv node precompute, via MFMA ----
__global__ __launch_bounds__(THREADS) void k_embed(const float* __restrict__ xin,
    const float* __restrict__ lw /*32x54*/, const float* __restrict__ lb,
    const float* __restrict__ w1 /*32x33*/, const float* __restrict__ w2 /*32x32*/,
    const float* __restrict__ attr_r, float* __restrict__ X,
    bf16* __restrict__ u, bf16* __restrict__ v, float* __restrict__ nr){
  __shared__ float ol[4][16][33];
  int wid  = (blockIdx.x*THREADS + threadIdx.x) >> 6;
  int wv   = threadIdx.x >> 6;
  int lane = threadIdx.x & 63;
  int cl = lane & 15;
  int kb = lane >> 4;
  short8v BL[2][2], BU[2], BV[2];
  #pragma unroll
  for (int g = 0; g < 2; g++){
    #pragma unroll
    for (int kc = 0; kc < 2; kc++){
      short8v t;
      #pragma unroll
      for (int j = 0; j < 8; j++){
        int k = kc*32 + kb*8 + j;
        t[j] = (k < 54) ? (short)bfbits(lw[(size_t)(g*16+cl)*54 + k]) : (short)0;
      }
      BL[g][kc] = t;
    }
    short8v tu, tv;
    #pragma unroll
    for (int j = 0; j < 8; j++){
      tu[j] = (short)bfbits(w1[(size_t)(g*16+cl)*33 + kb*8 + j]);
      tv[j] = (short)bfbits(w2[(size_t)(g*16+cl)*32 + kb*8 + j]);
    }
    BU[g] = tu; BV[g] = tv;
  }
  float bb0 = lb[cl], bb1 = lb[16+cl];
  float ar0 = attr_r[cl], ar1 = attr_r[16+cl];
  f32x4 zero; zero[0]=0.f; zero[1]=0.f; zero[2]=0.f; zero[3]=0.f;

  for (int t = 0; t < 8; t++){
    int nb = (wid*8 + t)*16;
    const float* xrow = xin + (size_t)(nb + cl)*54;
    short8v Ax0, Ax1;
    const float2* x2 = (const float2*)(xrow + kb*8);
    #pragma unroll
    for (int jj = 0; jj < 4; jj++){
      float2 tvv = x2[jj];
      Ax0[2*jj]   = (short)bfbits(tvv.x);
      Ax0[2*jj+1] = (short)bfbits(tvv.y);
    }
    #pragma unroll
    for (int j = 0; j < 8; j++){
      int k = 32 + kb*8 + j;
      Ax1[j] = (k < 54) ? (short)bfbits(xrow[k]) : (short)0;
    }
    f32x4 a0, a1;
    #pragma unroll
    for (int q = 0; q < 4; q++){ a0[q] = bb0; a1[q] = bb1; }
    f32x4 d0 = __builtin_amdgcn_mfma_f32_16x16x32_bf16(Ax0, BL[0][0], a0, 0, 0, 0);
    d0 = __builtin_amdgcn_mfma_f32_16x16x32_bf16(Ax1, BL[0][1], d0, 0, 0, 0);
    f32x4 d1 = __builtin_amdgcn_mfma_f32_16x16x32_bf16(Ax0, BL[1][0], a1, 0, 0, 0);
    d1 = __builtin_amdgcn_mfma_f32_16x16x32_bf16(Ax1, BL[1][1], d1, 0, 0, 0);
    #pragma unroll
    for (int r = 0; r < 4; r++){ d0[r] = lrelu(d0[r]); d1[r] = lrelu(d1[r]); }
    #pragma unroll
    for (int r = 0; r < 4; r++){
      int node = nb + kb*4 + r;
      float* srow = X + (size_t)node*32;
      srow[cl]      = d0[r];
      srow[16 + cl] = d1[r];
      ol[wv][kb*4 + r][cl]      = d0[r];
      ol[wv][kb*4 + r][16 + cl] = d1[r];
    }
    #pragma unroll
    for (int r = 0; r < 4; r++){
      float vsum = d0[r]*ar0 + d1[r]*ar1;
      vsum += __shfl_xor(vsum, 1, 16);
      vsum += __shfl_xor(vsum, 2, 16);
      vsum += __shfl_xor(vsum, 4, 16);
      vsum += __shfl_xor(vsum, 8, 16);
      if (cl == 0) nr[nb + kb*4 + r] = vsum;
    }
    __syncthreads();
    short8v Ao;
    #pragma unroll
    for (int j = 0; j < 8; j++) Ao[j] = (short)bfbits(ol[wv][cl][kb*8 + j]);
    f32x4 u0 = __builtin_amdgcn_mfma_f32_16x16x32_bf16(Ao, BU[0], zero, 0, 0, 0);
    f32x4 u1 = __builtin_amdgcn_mfma_f32_16x16x32_bf16(Ao, BU[1], zero, 0, 0, 0);
    f32x4 v0 = __builtin_amdgcn_mfma_f32_16x16x32_bf16(Ao, BV[0], zero, 0, 0, 0);
    f32x4 v1 = __builtin_amdgcn_mfma_f32_16x16x32_bf16(Ao, BV[1], zero, 0, 0, 0);
    #pragma unroll
    for (int r = 0; r < 4; r++){
      int node = nb + kb*4 + r;
      bf16* ur = u + (size_t)node*32;
      bf16* vr = v + (size_t)node*32;
      ur[cl]      = f2b(u0[r]);
      ur[16 + cl] = f2b(u1[r]);
      vr[cl]      = f2b(v0[r]);
      vr[16 + cl] = f2b(v1[r]);
    }
    __syncthreads();
  }
}

// ---------------- CSR build ----------------
__global__ __launch_bounds__(THREADS) void k_histrank(const int* __restrict__ ei,
    int* __restrict__ hist, int* __restrict__ rank){
  int e = blockIdx.x*THREADS + threadIdx.x;
  rank[e] = atomicAdd(hist + ei[NE + e], 1);
}

__global__ __launch_bounds__(THREADS) void k_scan1(const int* __restrict__ hist,
    int* __restrict__ rowptr, int* __restrict__ btot){
  __shared__ int sh[THREADS];
  int i = blockIdx.x*THREADS + threadIdx.x;
  int v = hist[i];
  sh[threadIdx.x] = v; __syncthreads();
  #pragma unroll
  for (int off = 1; off < THREADS; off <<= 1){
    int t = (threadIdx.x >= off) ? sh[threadIdx.x - off] : 0;
    __syncthreads(); sh[threadIdx.x] += t; __syncthreads();
  }
  rowptr[i] = sh[threadIdx.x] - v;
  if (threadIdx.x == THREADS-1) btot[blockIdx.x] = sh[THREADS-1];
}

__global__ __launch_bounds__(1024) void k_scan2(int* __restrict__ btot){
  __shared__ int sh[1024];
  int i = threadIdx.x;
  int v = btot[i];
  sh[i] = v; __syncthreads();
  for (int off = 1; off < 1024; off <<= 1){
    int t = (i >= off) ? sh[i - off] : 0;
    __syncthreads(); sh[i] += t; __syncthreads();
  }
  btot[i] = sh[i] - v;  // exclusive
}

__global__ __launch_bounds__(THREADS) void k_scan3(int* __restrict__ rowptr,
    const int* __restrict__ btot){
  int i = blockIdx.x*THREADS + threadIdx.x;
  rowptr[i] = rowptr[i] + btot[i >> 8];
  if (i == 0) rowptr[NN] = NE;
}

// ATOMIC-FREE placement: pos = rowptr[dst] + rank[e]; single 8B scattered store
__global__ __launch_bounds__(THREADS) void k_place(const int* __restrict__ ei,
    const float* __restrict__ ea, const int* __restrict__ rank,
    const int* __restrict__ rowptr, int2* __restrict__ epk){
  int e = blockIdx.x*THREADS + threadIdx.x;
  int d = ei[NE + e];
  int pos = rowptr[d] + rank[e];
  epk[pos] = make_int2(ei[e], __float_as_int(ea[e]));
}

// graph boundaries from sorted batch index
__global__ __launch_bounds__(THREADS) void k_gptr(const int* __restrict__ batch, int* __restrict__ gptr){
  int n = blockIdx.x*THREADS + threadIdx.x;
  int bc = batch[n];
  if (n == 0){ for (int g = 0; g <= bc; g++) gptr[g] = 0; }
  else {
    int pb = batch[n-1];
    if (pb != bc) for (int g = pb+1; g <= bc; g++) gptr[g] = n;
  }
  if (n == NN-1){ for (int g = bc+1; g <= NG; g++) gptr[g] = NN; }
}

// ---- GATConv node precompute: one THREAD per node (round-10 proven form) ----
__global__ __launch_bounds__(THREADS) void k_att_node(const float* __restrict__ X,
    const float* __restrict__ w, const float* __restrict__ a1, const float* __restrict__ a2,
    bf16* __restrict__ xt, float* __restrict__ s1, float* __restrict__ s2){
  int n = blockIdx.x*THREADS + threadIdx.x;
  float x[32];
  const float* xr = X + (size_t)n*32;
  #pragma unroll
  for (int k = 0; k < 32; k++) x[k] = xr[k];
  unsigned int* t2 = (unsigned int*)(xt + (size_t)n*32);
  float p1 = 0.f, p2 = 0.f;
  #pragma unroll 2
  for (int c2 = 0; c2 < 16; c2++){
    float t0=0.f, t1=0.f;
    #pragma unroll
    for (int k = 0; k < 32; k++){
      float xv = x[k];
      t0 += xv * w[(2*c2  )*32 + k];
      t1 += xv * w[(2*c2+1)*32 + k];
    }
    p1 += t0*a1[2*c2] + t1*a1[2*c2+1];
    if (a2) p2 += t0*a2[2*c2] + t1*a2[2*c2+1];
    t2[c2] = pack2(t0, t1);
  }
  s1[n] = p1;
  if (s2) s2[n] = p2;
}

// ---- GRU via MFMA ----
__global__ __launch_bounds__(THREADS) void k_gru_mfma(const bf16* __restrict__ HV,
    float* __restrict__ S,
    const float* __restrict__ wih, const float* __restrict__ whh,
    const float* __restrict__ bih, const float* __restrict__ bhh){
  int wid  = (blockIdx.x*THREADS + threadIdx.x) >> 6;
  int lane = threadIdx.x & 63;
  int cl = lane & 15;
  int kb = lane >> 4;
  short8v BW[12];
  #pragma unroll
  for (int g = 0; g < 6; g++){
    const float* wr = wih + (size_t)(g*16 + cl)*32 + kb*8;
    const float* vr = whh + (size_t)(g*16 + cl)*32 + kb*8;
    short8v bw, bv;
    #pragma unroll
    for (int j = 0; j < 8; j++){ bw[j] = (short)bfbits(wr[j]); bv[j] = (short)bfbits(vr[j]); }
    BW[g] = bw; BW[6+g] = bv;
  }
  float bI[6], bH[6];
  #pragma unroll
  for (int g = 0; g < 6; g++){ bI[g] = bih[g*16 + cl]; bH[g] = bhh[g*16 + cl]; }

  #pragma unroll 2
  for (int t = 0; t < 8; t++){
    int nb = (wid*8 + t) * 16;
    short8v Ah = *(const short8v*)(HV + (size_t)(nb + cl)*32 + kb*8);
    const float* xr = S + (size_t)(nb + cl)*32 + kb*8;
    short8v Ax;
    #pragma unroll
    for (int j = 0; j < 8; j++) Ax[j] = (short)bfbits(xr[j]);
    f32x4 gi[6], gh[6];
    #pragma unroll
    for (int g = 0; g < 6; g++){
      f32x4 a, b;
      #pragma unroll
      for (int q = 0; q < 4; q++){ a[q] = bI[g]; b[q] = bH[g]; }
      gi[g] = __builtin_amdgcn_mfma_f32_16x16x32_bf16(Ah, BW[g],   a, 0, 0, 0);
      gh[g] = __builtin_amdgcn_mfma_f32_16x16x32_bf16(Ax, BW[6+g], b, 0, 0, 0);
    }
    #pragma unroll
    for (int r = 0; r < 4; r++){
      int node = nb + kb*4 + r;
      float* srow = S + (size_t)node*32;
      float x0 = srow[cl], x1 = srow[16 + cl];
      float r0 = sigm(gi[0][r] + gh[0][r]);
      float z0 = sigm(gi[2][r] + gh[2][r]);
      float n0 = tanh_fast(gi[4][r] + r0*gh[4][r]);
      float r1 = sigm(gi[1][r] + gh[1][r]);
      float z1 = sigm(gi[3][r] + gh[3][r]);
      float n1 = tanh_fast(gi[5][r] + r1*gh[5][r]);
      srow[cl]      = fmaxf((1.f - z0)*n0 + z0*x0, 0.f);
      srow[16 + cl] = fmaxf((1.f - z1)*n1 + z1*x1, 0.f);
    }
  }
}

// ---------------- edge-parallel logits (GATEConv only) ----------------
__global__ __launch_bounds__(THREADS) void k_elog1(const int2* __restrict__ epk,
    const bf16* __restrict__ U,
    const float* __restrict__ w1 /*32x33*/, const float* __restrict__ attl,
    float* __restrict__ elog){
  int q  = threadIdx.x & 3;
  int lg = threadIdx.x >> 2;
  float wc[8], at[8];
  #pragma unroll
  for (int j = 0; j < 8; j++){
    wc[j] = w1[(q*8 + j)*33 + 32];
    at[j] = attl[q*8 + j];
  }
  int base = blockIdx.x * 512;
  #pragma unroll 2
  for (int i = 0; i < 8; i++){
    int p = base + i*64 + lg;
    int2 pk = epk[p];
    int si = pk.x;
    float a = __int_as_float(pk.y);
    short8v u8 = *(const short8v*)(U + (size_t)si*32 + q*8);
    float t = 0.f;
    #pragma unroll
    for (int j = 0; j < 8; j++) t += at[j]*lrelu(s2f(u8[j]) + a*wc[j]);
    t += __shfl_xor(t, 1, 4);
    t += __shfl_xor(t, 2, 4);
    if (q == 0) elog[p] = t;
  }
}

// ---- conv v2: max pass, then fused weight+sum+gather pass; one exp per edge ----
__global__ __launch_bounds__(THREADS) void k_conv(const int* __restrict__ rowptr,
    const int2* __restrict__ epk, const float* __restrict__ lg,
    const float* __restrict__ alsrc, const float* __restrict__ term,
    const bf16* __restrict__ ROWS, const float* __restrict__ bias,
    bf16* __restrict__ HV){
  int node = blockIdx.x*(THREADS/32) + (threadIdx.x >> 5);
  int c32 = threadIdx.x & 31;
  int ws = rowptr[node], we = rowptr[node+1];
  float tv = term[node];
  // pass A: segment max (lane-per-edge)
  float m = -INFINITY;
  for (int p0 = ws; p0 < we; p0 += 32){
    int p = p0 + c32;
    bool ok = p < we;
    int pc = ok ? p : ws;
    float sc = lg ? lg[pc] : alsrc[epk[pc].x];
    float l = ok ? lrelu(sc + tv) : -INFINITY;
    m = fmaxf(m, redmax32(l));
  }
  // pass B: per-edge weight once, denominator, gather with shfl broadcast
  int eg = c32 >> 2, cb = c32 & 3;
  float s = 0.f;
  float acc[8];
  #pragma unroll
  for (int j = 0; j < 8; j++) acc[j] = 0.f;
  for (int p0 = ws; p0 < we; p0 += 32){
    int p = p0 + c32;
    bool ok = p < we;
    int pc = ok ? p : ws;
    int siA = epk[pc].x;
    float sc = lg ? lg[pc] : alsrc[siA];
    float wme = ok ? __expf(lrelu(sc + tv) - m) : 0.f;
    s += redsum32(wme);
    #pragma unroll
    for (int s8 = 0; s8 < 32; s8 += 8){
      if (p0 + s8 >= we) break;
      float w = __shfl(wme, s8 + eg, 32);
      int si  = __shfl(siA, s8 + eg, 32);
      short8v r8 = *(const short8v*)(ROWS + (size_t)si*32 + cb*8);
      #pragma unroll
      for (int j = 0; j < 8; j++) acc[j] += s2f(r8[j]) * w;
    }
  }
  float inv = 1.f/(s + 1e-16f);
  #pragma unroll
  for (int j = 0; j < 8; j++){
    acc[j] += __shfl_xor(acc[j], 4, 32);
    acc[j] += __shfl_xor(acc[j], 8, 32);
    acc[j] += __shfl_xor(acc[j], 16, 32);
  }
  if (eg == 0){
    unsigned int o[4];
    #pragma unroll
    for (int j2 = 0; j2 < 4; j2++){
      float h0 = eluf(acc[2*j2  ]*inv + bias[cb*8 + 2*j2  ]);
      float h1 = eluf(acc[2*j2+1]*inv + bias[cb*8 + 2*j2+1]);
      o[j2] = pack2(h0, h1);
    }
    *(uint4*)(HV + (size_t)node*32 + cb*8) = make_uint4(o[0], o[1], o[2], o[3]);
  }
}

// ---------------- readout ----------------
__global__ __launch_bounds__(THREADS) void k_rsum(const int* __restrict__ gptr,
    const float* __restrict__ X, float* __restrict__ gout){
  int g = blockIdx.x*(THREADS/32) + (threadIdx.x >> 5);
  int c = threadIdx.x & 31;
  int gs = gptr[g], ge = gptr[g+1];
  float acc = 0.f;
  for (int n = gs; n < ge; n++) acc += X[(size_t)n*32 + c];
  gout[(size_t)g*32 + c] = fmaxf(acc, 0.f);
}

// q[k] = sum_c att_dst[c] * W[c][k]
__global__ void k_q(const float* __restrict__ w, const float* __restrict__ attd,
                    float* __restrict__ q){
  int k = threadIdx.x;
  float acc = 0.f;
  #pragma unroll
  for (int c = 0; c < 32; c++) acc += attd[c] * w[c*32 + k];
  q[k] = acc;
}

// one readout timestep: softmax over nodes of graph + weighted sum + GRU3
__global__ __launch_bounds__(THREADS) void k_rstep(const int* __restrict__ gptr,
    const float* __restrict__ anode, const bf16* __restrict__ XS,
    const float* __restrict__ q, const float* __restrict__ mbias,
    float* __restrict__ gout,
    const float* __restrict__ wih, const float* __restrict__ whh,
    const float* __restrict__ bih, const float* __restrict__ bhh){
  int g = blockIdx.x*(THREADS/32) + (threadIdx.x >> 5);
  int c = threadIdx.x & 31;
  float orow = gout[(size_t)g*32 + c];
  float ag = redsum32(orow * q[c]);
  int gs = gptr[g], ge = gptr[g+1];
  float m = -INFINITY, s = 0.f;
  for (int p0 = gs; p0 < ge; p0 += 32){
    int p = p0 + c;
    bool ok = p < ge;
    float lg = ok ? lrelu(anode[p] + ag) : -INFINITY;
    float cm = redmax32(lg);
    float mn = fmaxf(m, cm);
    float e = ok ? __expf(lg - mn) : 0.f;
    float cs = redsum32(e);
    s = s*__expf(m - mn) + cs;
    m = mn;
  }
  float inv = 1.f/(s + 1e-16f);
  float acc = 0.f;
  int n = gs;
  for (; n + 4 <= ge; n += 4){
    float e0 = __expf(lrelu(anode[n]   + ag) - m);
    float e1 = __expf(lrelu(anode[n+1] + ag) - m);
    float e2 = __expf(lrelu(anode[n+2] + ag) - m);
    float e3 = __expf(lrelu(anode[n+3] + ag) - m);
    acc += b2f(XS[(size_t)(n  )*32 + c])*e0 + b2f(XS[(size_t)(n+1)*32 + c])*e1
         + b2f(XS[(size_t)(n+2)*32 + c])*e2 + b2f(XS[(size_t)(n+3)*32 + c])*e3;
  }
  for (; n < ge; n++)
    acc += b2f(XS[(size_t)n*32 + c]) * __expf(lrelu(anode[n] + ag) - m);
  acc *= inv;
  float hv = eluf(acc + mbias[c]);
  gout[(size_t)g*32 + c] = gru_relu(hv, orow, c, wih, whh, bih, bhh);
}

// y = mish(out @ lin2^T + b)
__global__ __launch_bounds__(THREADS) void k_final(const float* __restrict__ out32,
    const float* __restrict__ w /*64x32*/, const float* __restrict__ b,
    float* __restrict__ y){
  int gid = blockIdx.x*THREADS + threadIdx.x;
  int g = gid >> 6, oc = gid & 63;
  const float* orow = out32 + (size_t)g*32;
  const float* wr = w + oc*32;
  float acc = b[oc];
  #pragma unroll
  for (int k = 0; k < 32; k++) acc += orow[k]*wr[k];
  float sp = fmaxf(acc, 0.f) + log1pf(expf(-fabsf(acc)));  // keep precise (final output)
  y[(size_t)g*64 + oc] = acc * tanhf(sp);
}

extern "C" void kernel_launch(void* const* d_in, const int* in_sizes, int n_in,
                              void* d_out, int out_size, void* d_ws, size_t ws_size,
                              hipStream_t stream){
  const float* x_in     = (const float*)d_in[0];
  const float* ea       = (const float*)d_in[1];
  const int*   ei       = (const int*)  d_in[2];
  const int*   batch    = (const int*)  d_in[3];
  const float* lin1_w   = (const float*)d_in[4];
  const float* lin1_b   = (const float*)d_in[5];
  const float* g_lin1_w = (const float*)d_in[6];
  const float* g_lin2_w = (const float*)d_in[7];
  const float* g_att_l  = (const float*)d_in[8];
  const float* g_att_r  = (const float*)d_in[9];
  const float* g_bias   = (const float*)d_in[10];
  const float* gru1_wih = (const float*)d_in[11];
  const float* gru1_whh = (const float*)d_in[12];
  const float* gru1_bih = (const float*)d_in[13];
  const float* gru1_bhh = (const float*)d_in[14];
  const float* a_lin_w  = (const float*)d_in[15];
  const float* a_att_src= (const float*)d_in[16];
  const float* a_att_dst= (const float*)d_in[17];
  const float* a_bias   = (const float*)d_in[18];
  const float* gru2_wih = (const float*)d_in[19];
  const float* gru2_whh = (const float*)d_in[20];
  const float* gru2_bih = (const float*)d_in[21];
  const float* gru2_bhh = (const float*)d_in[22];
  const float* m_lin_w  = (const float*)d_in[23];
  const float* m_att_src= (const float*)d_in[24];
  const float* m_att_dst= (const float*)d_in[25];
  const float* m_bias   = (const float*)d_in[26];
  const float* gru3_wih = (const float*)d_in[27];
  const float* gru3_whh = (const float*)d_in[28];
  const float* gru3_bih = (const float*)d_in[29];
  const float* gru3_bhh = (const float*)d_in[30];
  const float* lin2_w   = (const float*)d_in[31];
  const float* lin2_b   = (const float*)d_in[32];

  float* W = (float*)d_ws;
  float* X     = W;                      // NN*32 f32
  bf16*  BA    = (bf16*)(W + 8388608);   // NN*32 bf16 : u / h1 / xt / xs
  bf16*  BB    = (bf16*)(W + 12582912);  // NN*32 bf16 : v / h2
  int2*  EPK   = (int2*) (W + 16777216); // NE x (src, ea-bits)
  float* ELOG  = W + 20971520;           // NE raw GATEConv edge scores
  int*   RANK  = (int*)  (W + 23068672); // NE within-dst ranks
  int*   ROWPTR= (int*)  (W + 25165824); // NN+1 (pad)
  int*   HIST  = (int*)  (W + 25428032); // NN
  int*   BTOT  = (int*)  (W + 25690176); // 1024
  float* NS1   = W + 25691200;           // NN : nr / al / a_node
  float* NS2   = W + 25953344;           // NN : ar
  int*   GPTR  = (int*)  (W + 26215488); // NG+1 (pad)
  float* GOUT  = W + 26223744;           // NG*32
  float* Q     = W + 26485888;           // 32

  dim3 b(THREADS);
  const int gNode  = NN/THREADS;        // 1024
  const int gEdge  = NE/THREADS;        // 8192
  const int gElog1 = NE/512;            // 4096
  const int gNode32= NN/(THREADS/32);   // 32768
  const int gG32   = NG/(THREADS/32);   // 1024
  const int gMFMA  = NN/(16*8*4);       // 512

  // fused atom embedding + GATEConv node precompute (MFMA)
  k_embed<<<gMFMA, b, 0, stream>>>(x_in, lin1_w, lin1_b, g_lin1_w, g_lin2_w, g_att_r,
      X, BA, BB, NS1);

  // CSR build (dst-sorted; single atomic pass, atomic-free placement)
  k_filli<<<gNode, b, 0, stream>>>(HIST, 0, NN);
  k_histrank<<<gEdge, b, 0, stream>>>(ei, HIST, RANK);
  k_scan1<<<gNode, b, 0, stream>>>(HIST, ROWPTR, BTOT);
  k_scan2<<<1, 1024, 0, stream>>>(BTOT);
  k_scan3<<<gNode, b, 0, stream>>>(ROWPTR, BTOT);
  k_place<<<gEdge, b, 0, stream>>>(ei, ea, RANK, ROWPTR, EPK);
  k_gptr<<<gNode, b, 0, stream>>>(batch, GPTR);

  // GATEConv + GRU1
  k_elog1<<<gElog1, b, 0, stream>>>(EPK, BA, g_lin1_w, g_att_l, ELOG);
  k_conv<<<gNode32, b, 0, stream>>>(ROWPTR, EPK, ELOG, nullptr, NS1, BB, g_bias, BA);
  k_gru_mfma<<<gMFMA, b, 0, stream>>>(BA, X, gru1_wih, gru1_whh, gru1_bih, gru1_bhh);

  // GATConv + GRU2
  k_att_node<<<gNode, b, 0, stream>>>(X, a_lin_w, a_att_src, a_att_dst, BA, NS1, NS2);
  k_conv<<<gNode32, b, 0, stream>>>(ROWPTR, EPK, nullptr, NS1, NS2, BA, a_bias, BB);
  k_gru_mfma<<<gMFMA, b, 0, stream>>>(BB, X, gru2_wih, gru2_whh, gru2_bih, gru2_bhh);

  // readout
  k_rsum<<<gG32, b, 0, stream>>>(GPTR, X, GOUT);
  k_att_node<<<gNode, b, 0, stream>>>(X, m_lin_w, m_att_src, nullptr, BA, NS1, nullptr);
  k_q<<<1, 32, 0, stream>>>(m_lin_w, m_att_dst, Q);
  for (int t = 0; t < 2; t++){
    k_rstep<<<gG32, b, 0, stream>>>(GPTR, NS1, BA, Q, m_bias, GOUT,
        gru3_wih, gru3_whh, gru3_bih, gru3_bhh);
  }

  k_final<<<(NG*64)/THREADS, b, 0, stream>>>(GOUT, lin2_w, lin2_b, (float*)d_out);
}

// Round 14
// 503.128 us; speedup vs baseline: 1.6498x; 1.0649x over previous
//
#include <hip/hip_runtime.h>
#include <hip/hip_bf16.h>
#include <math.h>

#define NN 262144
#define NE 2097152
#define NG 8192
#define THREADS 256

typedef __hip_bfloat16 bf16;
typedef __attribute__((ext_vector_type(8))) short short8v;   // 8 bf16 (4 VGPRs)
typedef __attribute__((ext_vector_type(4))) float f32x4;

static __device__ __forceinline__ float lrelu(float x){ return x > 0.f ? x : 0.01f*x; }
static __device__ __forceinline__ float eluf(float x){ return x > 0.f ? x : __expf(x) - 1.f; }
static __device__ __forceinline__ float sigm(float x){ return 1.f/(1.f + __expf(-x)); }
static __device__ __forceinline__ float tanh_fast(float x){
  float e = __expf(2.f*x); return 1.f - 2.f/(e + 1.f);
}
static __device__ __forceinline__ float b2f(bf16 v){ return __bfloat162float(v); }
static __device__ __forceinline__ bf16 f2b(float v){ return __float2bfloat16(v); }
// bit-reinterpret a raw bf16 (held in a short) to float — NEVER value-convert!
static __device__ __forceinline__ float s2f(short s){
  return __uint_as_float(((unsigned int)(unsigned short)s) << 16);
}

static __device__ __forceinline__ unsigned short bfbits(float f){
  union { bf16 b; unsigned short s; } u; u.b = f2b(f); return u.s;
}
static __device__ __forceinline__ unsigned int pack2(float lo, float hi){
  return (unsigned int)bfbits(lo) | ((unsigned int)bfbits(hi) << 16);
}

static __device__ __forceinline__ float redsum32(float t){
  #pragma unroll
  for (int o = 16; o > 0; o >>= 1) t += __shfl_xor(t, o, 32);
  return t;
}
static __device__ __forceinline__ float redmax32(float t){
  #pragma unroll
  for (int o = 16; o > 0; o >>= 1) t = fmaxf(t, __shfl_xor(t, o, 32));
  return t;
}

// GRU fused helper for the tiny readout kernel (32 lanes = one row)
static __device__ __forceinline__ float gru_relu(float hv, float xv, int c,
    const float* __restrict__ wih, const float* __restrict__ whh,
    const float* __restrict__ bih, const float* __restrict__ bhh){
  float gr = bih[c], gz = bih[32+c], gn = bih[64+c];
  float hr = bhh[c], hz = bhh[32+c], hn = bhh[64+c];
  #pragma unroll 8
  for (int k = 0; k < 32; k++){
    float hk = __shfl(hv, k, 32);
    float xk = __shfl(xv, k, 32);
    gr += hk*wih[(     c)*32 + k];
    gz += hk*wih[(32 + c)*32 + k];
    gn += hk*wih[(64 + c)*32 + k];
    hr += xk*whh[(     c)*32 + k];
    hz += xk*whh[(32 + c)*32 + k];
    hn += xk*whh[(64 + c)*32 + k];
  }
  float r = sigm(gr + hr), z = sigm(gz + hz);
  float nn2 = tanh_fast(gn + r*hn);
  return fmaxf((1.f - z)*nn2 + z*xv, 0.f);
}

__global__ __launch_bounds__(THREADS) void k_filli(int* __restrict__ p, int v, int n){
  int i = blockIdx.x*THREADS + threadIdx.x;
  if (i < n) p[i] = v;
}

// ================= FRONT mega-kernel: embed (MFMA) ∥ histrank ∥ gptr ==========
#define FB_EMBED 512
#define FB_HIST  8192
#define FB_GPTR  1024

__global__ __launch_bounds__(THREADS) void k_front(
    // embed args
    const float* __restrict__ xin, const float* __restrict__ lw, const float* __restrict__ lb,
    const float* __restrict__ w1, const float* __restrict__ w2,
    const float* __restrict__ attr_r, float* __restrict__ X,
    bf16* __restrict__ u, bf16* __restrict__ v, float* __restrict__ nr,
    // histrank args
    const int* __restrict__ ei, int* __restrict__ hist, int* __restrict__ rank,
    // gptr args
    const int* __restrict__ batch, int* __restrict__ gptr){
  __shared__ float ol[4][16][33];
  int bid = blockIdx.x;
  if (bid < FB_EMBED){
    // ---- embed body (MFMA) ----
    int wid  = bid*4 + (threadIdx.x >> 6);
    int wv   = threadIdx.x >> 6;
    int lane = threadIdx.x & 63;
    int cl = lane & 15;
    int kb = lane >> 4;
    short8v BL[2][2], BU[2], BV[2];
    #pragma unroll
    for (int g = 0; g < 2; g++){
      #pragma unroll
      for (int kc = 0; kc < 2; kc++){
        short8v t;
        #pragma unroll
        for (int j = 0; j < 8; j++){
          int k = kc*32 + kb*8 + j;
          t[j] = (k < 54) ? (short)bfbits(lw[(size_t)(g*16+cl)*54 + k]) : (short)0;
        }
        BL[g][kc] = t;
      }
      short8v tu, tv;
      #pragma unroll
      for (int j = 0; j < 8; j++){
        tu[j] = (short)bfbits(w1[(size_t)(g*16+cl)*33 + kb*8 + j]);
        tv[j] = (short)bfbits(w2[(size_t)(g*16+cl)*32 + kb*8 + j]);
      }
      BU[g] = tu; BV[g] = tv;
    }
    float bb0 = lb[cl], bb1 = lb[16+cl];
    float ar0 = attr_r[cl], ar1 = attr_r[16+cl];
    f32x4 zero; zero[0]=0.f; zero[1]=0.f; zero[2]=0.f; zero[3]=0.f;

    for (int t = 0; t < 8; t++){
      int nb = (wid*8 + t)*16;
      const float* xrow = xin + (size_t)(nb + cl)*54;
      short8v Ax0, Ax1;
      const float2* x2 = (const float2*)(xrow + kb*8);
      #pragma unroll
      for (int jj = 0; jj < 4; jj++){
        float2 tvv = x2[jj];
        Ax0[2*jj]   = (short)bfbits(tvv.x);
        Ax0[2*jj+1] = (short)bfbits(tvv.y);
      }
      #pragma unroll
      for (int j = 0; j < 8; j++){
        int k = 32 + kb*8 + j;
        Ax1[j] = (k < 54) ? (short)bfbits(xrow[k]) : (short)0;
      }
      f32x4 a0, a1;
      #pragma unroll
      for (int q = 0; q < 4; q++){ a0[q] = bb0; a1[q] = bb1; }
      f32x4 d0 = __builtin_amdgcn_mfma_f32_16x16x32_bf16(Ax0, BL[0][0], a0, 0, 0, 0);
      d0 = __builtin_amdgcn_mfma_f32_16x16x32_bf16(Ax1, BL[0][1], d0, 0, 0, 0);
      f32x4 d1 = __builtin_amdgcn_mfma_f32_16x16x32_bf16(Ax0, BL[1][0], a1, 0, 0, 0);
      d1 = __builtin_amdgcn_mfma_f32_16x16x32_bf16(Ax1, BL[1][1], d1, 0, 0, 0);
      #pragma unroll
      for (int r = 0; r < 4; r++){ d0[r] = lrelu(d0[r]); d1[r] = lrelu(d1[r]); }
      #pragma unroll
      for (int r = 0; r < 4; r++){
        int node = nb + kb*4 + r;
        float* srow = X + (size_t)node*32;
        srow[cl]      = d0[r];
        srow[16 + cl] = d1[r];
        ol[wv][kb*4 + r][cl]      = d0[r];
        ol[wv][kb*4 + r][16 + cl] = d1[r];
      }
      #pragma unroll
      for (int r = 0; r < 4; r++){
        float vsum = d0[r]*ar0 + d1[r]*ar1;
        vsum += __shfl_xor(vsum, 1, 16);
        vsum += __shfl_xor(vsum, 2, 16);
        vsum += __shfl_xor(vsum, 4, 16);
        vsum += __shfl_xor(vsum, 8, 16);
        if (cl == 0) nr[nb + kb*4 + r] = vsum;
      }
      __syncthreads();
      short8v Ao;
      #pragma unroll
      for (int j = 0; j < 8; j++) Ao[j] = (short)bfbits(ol[wv][cl][kb*8 + j]);
      f32x4 u0 = __builtin_amdgcn_mfma_f32_16x16x32_bf16(Ao, BU[0], zero, 0, 0, 0);
      f32x4 u1 = __builtin_amdgcn_mfma_f32_16x16x32_bf16(Ao, BU[1], zero, 0, 0, 0);
      f32x4 v0 = __builtin_amdgcn_mfma_f32_16x16x32_bf16(Ao, BV[0], zero, 0, 0, 0);
      f32x4 v1 = __builtin_amdgcn_mfma_f32_16x16x32_bf16(Ao, BV[1], zero, 0, 0, 0);
      #pragma unroll
      for (int r = 0; r < 4; r++){
        int node = nb + kb*4 + r;
        bf16* ur = u + (size_t)node*32;
        bf16* vr = v + (size_t)node*32;
        ur[cl]      = f2b(u0[r]);
        ur[16 + cl] = f2b(u1[r]);
        vr[cl]      = f2b(v0[r]);
        vr[16 + cl] = f2b(v1[r]);
      }
      __syncthreads();
    }
  } else if (bid < FB_EMBED + FB_HIST){
    // ---- histrank body ----
    int e = (bid - FB_EMBED)*THREADS + threadIdx.x;
    rank[e] = atomicAdd(hist + ei[NE + e], 1);
  } else {
    // ---- gptr body ----
    int n = (bid - FB_EMBED - FB_HIST)*THREADS + threadIdx.x;
    int bc = batch[n];
    if (n == 0){ for (int g = 0; g <= bc; g++) gptr[g] = 0; }
    else {
      int pb = batch[n-1];
      if (pb != bc) for (int g = pb+1; g <= bc; g++) gptr[g] = n;
    }
    if (n == NN-1){ for (int g = bc+1; g <= NG; g++) gptr[g] = NN; }
  }
}

// ---------------- scans ----------------
__global__ __launch_bounds__(THREADS) void k_scan1(const int* __restrict__ hist,
    int* __restrict__ rowptr, int* __restrict__ btot){
  __shared__ int sh[THREADS];
  int i = blockIdx.x*THREADS + threadIdx.x;
  int v = hist[i];
  sh[threadIdx.x] = v; __syncthreads();
  #pragma unroll
  for (int off = 1; off < THREADS; off <<= 1){
    int t = (threadIdx.x >= off) ? sh[threadIdx.x - off] : 0;
    __syncthreads(); sh[threadIdx.x] += t; __syncthreads();
  }
  rowptr[i] = sh[threadIdx.x] - v;
  if (threadIdx.x == THREADS-1) btot[blockIdx.x] = sh[THREADS-1];
}

__global__ __launch_bounds__(1024) void k_scan2(int* __restrict__ btot){
  __shared__ int sh[1024];
  int i = threadIdx.x;
  int v = btot[i];
  sh[i] = v; __syncthreads();
  for (int off = 1; off < 1024; off <<= 1){
    int t = (i >= off) ? sh[i - off] : 0;
    __syncthreads(); sh[i] += t; __syncthreads();
  }
  btot[i] = sh[i] - v;  // exclusive
}

__global__ __launch_bounds__(THREADS) void k_scan3(int* __restrict__ rowptr,
    const int* __restrict__ btot){
  int i = blockIdx.x*THREADS + threadIdx.x;
  rowptr[i] = rowptr[i] + btot[i >> 8];
  if (i == 0) rowptr[NN] = NE;
}

// ATOMIC-FREE placement: pos = rowptr[dst] + rank[e]; single 8B scattered store
__global__ __launch_bounds__(THREADS) void k_place(const int* __restrict__ ei,
    const float* __restrict__ ea, const int* __restrict__ rank,
    const int* __restrict__ rowptr, int2* __restrict__ epk){
  int e = blockIdx.x*THREADS + threadIdx.x;
  int d = ei[NE + e];
  int pos = rowptr[d] + rank[e];
  epk[pos] = make_int2(ei[e], __float_as_int(ea[e]));
}

// ---- GATConv node precompute: one THREAD per node ----
__global__ __launch_bounds__(THREADS) void k_att_node(const float* __restrict__ X,
    const float* __restrict__ w, const float* __restrict__ a1, const float* __restrict__ a2,
    bf16* __restrict__ xt, float* __restrict__ s1, float* __restrict__ s2){
  int n = blockIdx.x*THREADS + threadIdx.x;
  float x[32];
  const float* xr = X + (size_t)n*32;
  #pragma unroll
  for (int k = 0; k < 32; k++) x[k] = xr[k];
  unsigned int* t2 = (unsigned int*)(xt + (size_t)n*32);
  float p1 = 0.f, p2 = 0.f;
  #pragma unroll 2
  for (int c2 = 0; c2 < 16; c2++){
    float t0=0.f, t1=0.f;
    #pragma unroll
    for (int k = 0; k < 32; k++){
      float xv = x[k];
      t0 += xv * w[(2*c2  )*32 + k];
      t1 += xv * w[(2*c2+1)*32 + k];
    }
    p1 += t0*a1[2*c2] + t1*a1[2*c2+1];
    if (a2) p2 += t0*a2[2*c2] + t1*a2[2*c2+1];
    t2[c2] = pack2(t0, t1);
  }
  s1[n] = p1;
  if (s2) s2[n] = p2;
}

// ---- GRU via MFMA ----
__global__ __launch_bounds__(THREADS) void k_gru_mfma(const bf16* __restrict__ HV,
    float* __restrict__ S,
    const float* __restrict__ wih, const float* __restrict__ whh,
    const float* __restrict__ bih, const float* __restrict__ bhh){
  int wid  = (blockIdx.x*THREADS + threadIdx.x) >> 6;
  int lane = threadIdx.x & 63;
  int cl = lane & 15;
  int kb = lane >> 4;
  short8v BW[12];
  #pragma unroll
  for (int g = 0; g < 6; g++){
    const float* wr = wih + (size_t)(g*16 + cl)*32 + kb*8;
    const float* vr = whh + (size_t)(g*16 + cl)*32 + kb*8;
    short8v bw, bv;
    #pragma unroll
    for (int j = 0; j < 8; j++){ bw[j] = (short)bfbits(wr[j]); bv[j] = (short)bfbits(vr[j]); }
    BW[g] = bw; BW[6+g] = bv;
  }
  float bI[6], bH[6];
  #pragma unroll
  for (int g = 0; g < 6; g++){ bI[g] = bih[g*16 + cl]; bH[g] = bhh[g*16 + cl]; }

  #pragma unroll 2
  for (int t = 0; t < 8; t++){
    int nb = (wid*8 + t) * 16;
    short8v Ah = *(const short8v*)(HV + (size_t)(nb + cl)*32 + kb*8);
    const float* xr = S + (size_t)(nb + cl)*32 + kb*8;
    short8v Ax;
    #pragma unroll
    for (int j = 0; j < 8; j++) Ax[j] = (short)bfbits(xr[j]);
    f32x4 gi[6], gh[6];
    #pragma unroll
    for (int g = 0; g < 6; g++){
      f32x4 a, b;
      #pragma unroll
      for (int q = 0; q < 4; q++){ a[q] = bI[g]; b[q] = bH[g]; }
      gi[g] = __builtin_amdgcn_mfma_f32_16x16x32_bf16(Ah, BW[g],   a, 0, 0, 0);
      gh[g] = __builtin_amdgcn_mfma_f32_16x16x32_bf16(Ax, BW[6+g], b, 0, 0, 0);
    }
    #pragma unroll
    for (int r = 0; r < 4; r++){
      int node = nb + kb*4 + r;
      float* srow = S + (size_t)node*32;
      float x0 = srow[cl], x1 = srow[16 + cl];
      float r0 = sigm(gi[0][r] + gh[0][r]);
      float z0 = sigm(gi[2][r] + gh[2][r]);
      float n0 = tanh_fast(gi[4][r] + r0*gh[4][r]);
      float r1 = sigm(gi[1][r] + gh[1][r]);
      float z1 = sigm(gi[3][r] + gh[3][r]);
      float n1 = tanh_fast(gi[5][r] + r1*gh[5][r]);
      srow[cl]      = fmaxf((1.f - z0)*n0 + z0*x0, 0.f);
      srow[16 + cl] = fmaxf((1.f - z1)*n1 + z1*x1, 0.f);
    }
  }
}

// ---------------- edge-parallel logits (GATEConv only) ----------------
__global__ __launch_bounds__(THREADS) void k_elog1(const int2* __restrict__ epk,
    const bf16* __restrict__ U,
    const float* __restrict__ w1 /*32x33*/, const float* __restrict__ attl,
    float* __restrict__ elog){
  int q  = threadIdx.x & 3;
  int lg = threadIdx.x >> 2;
  float wc[8], at[8];
  #pragma unroll
  for (int j = 0; j < 8; j++){
    wc[j] = w1[(q*8 + j)*33 + 32];
    at[j] = attl[q*8 + j];
  }
  int base = blockIdx.x * 512;
  #pragma unroll 2
  for (int i = 0; i < 8; i++){
    int p = base + i*64 + lg;
    int2 pk = epk[p];
    int si = pk.x;
    float a = __int_as_float(pk.y);
    short8v u8 = *(const short8v*)(U + (size_t)si*32 + q*8);
    float t = 0.f;
    #pragma unroll
    for (int j = 0; j < 8; j++) t += at[j]*lrelu(s2f(u8[j]) + a*wc[j]);
    t += __shfl_xor(t, 1, 4);
    t += __shfl_xor(t, 2, 4);
    if (q == 0) elog[p] = t;
  }
}

// ---- conv v2: max pass, then fused weight+sum+gather pass; one exp per edge ----
__global__ __launch_bounds__(THREADS) void k_conv(const int* __restrict__ rowptr,
    const int2* __restrict__ epk, const float* __restrict__ lg,
    const float* __restrict__ alsrc, const float* __restrict__ term,
    const bf16* __restrict__ ROWS, const float* __restrict__ bias,
    bf16* __restrict__ HV){
  int node = blockIdx.x*(THREADS/32) + (threadIdx.x >> 5);
  int c32 = threadIdx.x & 31;
  int ws = rowptr[node], we = rowptr[node+1];
  float tv = term[node];
  float m = -INFINITY;
  for (int p0 = ws; p0 < we; p0 += 32){
    int p = p0 + c32;
    bool ok = p < we;
    int pc = ok ? p : ws;
    float sc = lg ? lg[pc] : alsrc[epk[pc].x];
    float l = ok ? lrelu(sc + tv) : -INFINITY;
    m = fmaxf(m, redmax32(l));
  }
  int eg = c32 >> 2, cb = c32 & 3;
  float s = 0.f;
  float acc[8];
  #pragma unroll
  for (int j = 0; j < 8; j++) acc[j] = 0.f;
  for (int p0 = ws; p0 < we; p0 += 32){
    int p = p0 + c32;
    bool ok = p < we;
    int pc = ok ? p : ws;
    int siA = epk[pc].x;
    float sc = lg ? lg[pc] : alsrc[siA];
    float wme = ok ? __expf(lrelu(sc + tv) - m) : 0.f;
    s += redsum32(wme);
    #pragma unroll
    for (int s8 = 0; s8 < 32; s8 += 8){
      if (p0 + s8 >= we) break;
      float w = __shfl(wme, s8 + eg, 32);
      int si  = __shfl(siA, s8 + eg, 32);
      short8v r8 = *(const short8v*)(ROWS + (size_t)si*32 + cb*8);
      #pragma unroll
      for (int j = 0; j < 8; j++) acc[j] += s2f(r8[j]) * w;
    }
  }
  float inv = 1.f/(s + 1e-16f);
  #pragma unroll
  for (int j = 0; j < 8; j++){
    acc[j] += __shfl_xor(acc[j], 4, 32);
    acc[j] += __shfl_xor(acc[j], 8, 32);
    acc[j] += __shfl_xor(acc[j], 16, 32);
  }
  if (eg == 0){
    unsigned int o[4];
    #pragma unroll
    for (int j2 = 0; j2 < 4; j2++){
      float h0 = eluf(acc[2*j2  ]*inv + bias[cb*8 + 2*j2  ]);
      float h1 = eluf(acc[2*j2+1]*inv + bias[cb*8 + 2*j2+1]);
      o[j2] = pack2(h0, h1);
    }
    *(uint4*)(HV + (size_t)node*32 + cb*8) = make_uint4(o[0], o[1], o[2], o[3]);
  }
}

// ============== TAIL mega-kernel: rsum ∥ att_node(m) ∥ q =====================
#define TB_RSUM 1024
#define TB_ATT  1024

__global__ __launch_bounds__(THREADS) void k_tail(const int* __restrict__ gptr,
    const float* __restrict__ X, float* __restrict__ gout,
    const float* __restrict__ mw, const float* __restrict__ msrc,
    bf16* __restrict__ xs, float* __restrict__ anode,
    const float* __restrict__ mattd, float* __restrict__ q){
  int bid = blockIdx.x;
  if (bid < TB_RSUM){
    int g = bid*(THREADS/32) + (threadIdx.x >> 5);
    int c = threadIdx.x & 31;
    int gs = gptr[g], ge = gptr[g+1];
    float acc = 0.f;
    for (int n = gs; n < ge; n++) acc += X[(size_t)n*32 + c];
    gout[(size_t)g*32 + c] = fmaxf(acc, 0.f);
  } else if (bid < TB_RSUM + TB_ATT){
    int n = (bid - TB_RSUM)*THREADS + threadIdx.x;
    float x[32];
    const float* xr = X + (size_t)n*32;
    #pragma unroll
    for (int k = 0; k < 32; k++) x[k] = xr[k];
    unsigned int* t2 = (unsigned int*)(xs + (size_t)n*32);
    float p1 = 0.f;
    #pragma unroll 2
    for (int c2 = 0; c2 < 16; c2++){
      float t0=0.f, t1=0.f;
      #pragma unroll
      for (int k = 0; k < 32; k++){
        float xv = x[k];
        t0 += xv * mw[(2*c2  )*32 + k];
        t1 += xv * mw[(2*c2+1)*32 + k];
      }
      p1 += t0*msrc[2*c2] + t1*msrc[2*c2+1];
      t2[c2] = pack2(t0, t1);
    }
    anode[n] = p1;
  } else {
    int k = threadIdx.x;
    if (k < 32){
      float acc = 0.f;
      #pragma unroll
      for (int c = 0; c < 32; c++) acc += mattd[c] * mw[c*32 + k];
      q[k] = acc;
    }
  }
}

// one readout timestep: softmax over nodes of graph + weighted sum + GRU3
__global__ __launch_bounds__(THREADS) void k_rstep(const int* __restrict__ gptr,
    const float* __restrict__ anode, const bf16* __restrict__ XS,
    const float* __restrict__ q, const float* __restrict__ mbias,
    float* __restrict__ gout,
    const float* __restrict__ wih, const float* __restrict__ whh,
    const float* __restrict__ bih, const float* __restrict__ bhh){
  int g = blockIdx.x*(THREADS/32) + (threadIdx.x >> 5);
  int c = threadIdx.x & 31;
  float orow = gout[(size_t)g*32 + c];
  float ag = redsum32(orow * q[c]);
  int gs = gptr[g], ge = gptr[g+1];
  float m = -INFINITY, s = 0.f;
  for (int p0 = gs; p0 < ge; p0 += 32){
    int p = p0 + c;
    bool ok = p < ge;
    float lg = ok ? lrelu(anode[p] + ag) : -INFINITY;
    float cm = redmax32(lg);
    float mn = fmaxf(m, cm);
    float e = ok ? __expf(lg - mn) : 0.f;
    float cs = redsum32(e);
    s = s*__expf(m - mn) + cs;
    m = mn;
  }
  float inv = 1.f/(s + 1e-16f);
  float acc = 0.f;
  int n = gs;
  for (; n + 4 <= ge; n += 4){
    float e0 = __expf(lrelu(anode[n]   + ag) - m);
    float e1 = __expf(lrelu(anode[n+1] + ag) - m);
    float e2 = __expf(lrelu(anode[n+2] + ag) - m);
    float e3 = __expf(lrelu(anode[n+3] + ag) - m);
    acc += b2f(XS[(size_t)(n  )*32 + c])*e0 + b2f(XS[(size_t)(n+1)*32 + c])*e1
         + b2f(XS[(size_t)(n+2)*32 + c])*e2 + b2f(XS[(size_t)(n+3)*32 + c])*e3;
  }
  for (; n < ge; n++)
    acc += b2f(XS[(size_t)n*32 + c]) * __expf(lrelu(anode[n] + ag) - m);
  acc *= inv;
  float hv = eluf(acc + mbias[c]);
  gout[(size_t)g*32 + c] = gru_relu(hv, orow, c, wih, whh, bih, bhh);
}

// y = mish(out @ lin2^T + b)
__global__ __launch_bounds__(THREADS) void k_final(const float* __restrict__ out32,
    const float* __restrict__ w /*64x32*/, const float* __restrict__ b,
    float* __restrict__ y){
  int gid = blockIdx.x*THREADS + threadIdx.x;
  int g = gid >> 6, oc = gid & 63;
  const float* orow = out32 + (size_t)g*32;
  const float* wr = w + oc*32;
  float acc = b[oc];
  #pragma unroll
  for (int k = 0; k < 32; k++) acc += orow[k]*wr[k];
  float sp = fmaxf(acc, 0.f) + log1pf(expf(-fabsf(acc)));  // keep precise (final output)
  y[(size_t)g*64 + oc] = acc * tanhf(sp);
}

extern "C" void kernel_launch(void* const* d_in, const int* in_sizes, int n_in,
                              void* d_out, int out_size, void* d_ws, size_t ws_size,
                              hipStream_t stream){
  const float* x_in     = (const float*)d_in[0];
  const float* ea       = (const float*)d_in[1];
  const int*   ei       = (const int*)  d_in[2];
  const int*   batch    = (const int*)  d_in[3];
  const float* lin1_w   = (const float*)d_in[4];
  const float* lin1_b   = (const float*)d_in[5];
  const float* g_lin1_w = (const float*)d_in[6];
  const float* g_lin2_w = (const float*)d_in[7];
  const float* g_att_l  = (const float*)d_in[8];
  const float* g_att_r  = (const float*)d_in[9];
  const float* g_bias   = (const float*)d_in[10];
  const float* gru1_wih = (const float*)d_in[11];
  const float* gru1_whh = (const float*)d_in[12];
  const float* gru1_bih = (const float*)d_in[13];
  const float* gru1_bhh = (const float*)d_in[14];
  const float* a_lin_w  = (const float*)d_in[15];
  const float* a_att_src= (const float*)d_in[16];
  const float* a_att_dst= (const float*)d_in[17];
  const float* a_bias   = (const float*)d_in[18];
  const float* gru2_wih = (const float*)d_in[19];
  const float* gru2_whh = (const float*)d_in[20];
  const float* gru2_bih = (const float*)d_in[21];
  const float* gru2_bhh = (const float*)d_in[22];
  const float* m_lin_w  = (const float*)d_in[23];
  const float* m_att_src= (const float*)d_in[24];
  const float* m_att_dst= (const float*)d_in[25];
  const float* m_bias   = (const float*)d_in[26];
  const float* gru3_wih = (const float*)d_in[27];
  const float* gru3_whh = (const float*)d_in[28];
  const float* gru3_bih = (const float*)d_in[29];
  const float* gru3_bhh = (const float*)d_in[30];
  const float* lin2_w   = (const float*)d_in[31];
  const float* lin2_b   = (const float*)d_in[32];

  float* W = (float*)d_ws;
  float* X     = W;                      // NN*32 f32
  bf16*  BA    = (bf16*)(W + 8388608);   // NN*32 bf16 : u / h1 / xt / xs
  bf16*  BB    = (bf16*)(W + 12582912);  // NN*32 bf16 : v / h2
  int2*  EPK   = (int2*) (W + 16777216); // NE x (src, ea-bits)
  float* ELOG  = W + 20971520;           // NE raw GATEConv edge scores
  int*   RANK  = (int*)  (W + 23068672); // NE within-dst ranks
  int*   ROWPTR= (int*)  (W + 25165824); // NN+1 (pad)
  int*   HIST  = (int*)  (W + 25428032); // NN
  int*   BTOT  = (int*)  (W + 25690176); // 1024
  float* NS1   = W + 25691200;           // NN : nr / al / a_node
  float* NS2   = W + 25953344;           // NN : ar
  int*   GPTR  = (int*)  (W + 26215488); // NG+1 (pad)
  float* GOUT  = W + 26223744;           // NG*32
  float* Q     = W + 26485888;           // 32

  dim3 b(THREADS);
  const int gNode  = NN/THREADS;        // 1024
  const int gEdge  = NE/THREADS;        // 8192
  const int gElog1 = NE/512;            // 4096
  const int gNode32= NN/(THREADS/32);   // 32768
  const int gG32   = NG/(THREADS/32);   // 1024
  const int gMFMA  = NN/(16*8*4);       // 512

  // zero HIST (must precede k_front's histrank section)
  k_filli<<<gNode, b, 0, stream>>>(HIST, 0, NN);

  // FRONT: embed (MFMA) ∥ histrank (atomics) ∥ gptr — data-independent
  k_front<<<FB_EMBED + FB_HIST + FB_GPTR, b, 0, stream>>>(
      x_in, lin1_w, lin1_b, g_lin1_w, g_lin2_w, g_att_r, X, BA, BB, NS1,
      ei, HIST, RANK, batch, GPTR);

  // scans + atomic-free placement
  k_scan1<<<gNode, b, 0, stream>>>(HIST, ROWPTR, BTOT);
  k_scan2<<<1, 1024, 0, stream>>>(BTOT);
  k_scan3<<<gNode, b, 0, stream>>>(ROWPTR, BTOT);
  k_place<<<gEdge, b, 0, stream>>>(ei, ea, RANK, ROWPTR, EPK);

  // GATEConv + GRU1
  k_elog1<<<gElog1, b, 0, stream>>>(EPK, BA, g_lin1_w, g_att_l, ELOG);
  k_conv<<<gNode32, b, 0, stream>>>(ROWPTR, EPK, ELOG, nullptr, NS1, BB, g_bias, BA);
  k_gru_mfma<<<gMFMA, b, 0, stream>>>(BA, X, gru1_wih, gru1_whh, gru1_bih, gru1_bhh);

  // GATConv + GRU2
  k_att_node<<<gNode, b, 0, stream>>>(X, a_lin_w, a_att_src, a_att_dst, BA, NS1, NS2);
  k_conv<<<gNode32, b, 0, stream>>>(ROWPTR, EPK, nullptr, NS1, NS2, BA, a_bias, BB);
  k_gru_mfma<<<gMFMA, b, 0, stream>>>(BB, X, gru2_wih, gru2_whh, gru2_bih, gru2_bhh);

  // TAIL: rsum ∥ readout att_node ∥ q — data-independent, all need X-after-gru2
  k_tail<<<TB_RSUM + TB_ATT + 1, b, 0, stream>>>(GPTR, X, GOUT,
      m_lin_w, m_att_src, BA, NS1, m_att_dst, Q);

  for (int t = 0; t < 2; t++){
    k_rstep<<<gG32, b, 0, stream>>>(GPTR, NS1, BA, Q, m_bias, GOUT,
        gru3_wih, gru3_whh, gru3_bih, gru3_bhh);
  }

  k_final<<<(NG*64)/THREADS, b, 0, stream>>>(GOUT, lin2_w, lin2_b, (float*)d_out);
}

// Round 15
// 486.222 us; speedup vs baseline: 1.7072x; 1.0348x over previous
//
#include <hip/hip_runtime.h>
#include <hip/hip_bf16.h>
#include <math.h>

#define NN 262144
#define NE 2097152
#define NG 8192
#define THREADS 256

typedef __hip_bfloat16 bf16;
typedef __attribute__((ext_vector_type(8))) short short8v;   // 8 bf16 (4 VGPRs)
typedef __attribute__((ext_vector_type(4))) float f32x4;

static __device__ __forceinline__ float lrelu(float x){ return x > 0.f ? x : 0.01f*x; }
static __device__ __forceinline__ float eluf(float x){ return x > 0.f ? x : __expf(x) - 1.f; }
static __device__ __forceinline__ float sigm(float x){ return 1.f/(1.f + __expf(-x)); }
static __device__ __forceinline__ float tanh_fast(float x){
  float e = __expf(2.f*x); return 1.f - 2.f/(e + 1.f);
}
static __device__ __forceinline__ float b2f(bf16 v){ return __bfloat162float(v); }
static __device__ __forceinline__ bf16 f2b(float v){ return __float2bfloat16(v); }
// bit-reinterpret a raw bf16 (held in a short) to float — NEVER value-convert!
static __device__ __forceinline__ float s2f(short s){
  return __uint_as_float(((unsigned int)(unsigned short)s) << 16);
}

static __device__ __forceinline__ unsigned short bfbits(float f){
  union { bf16 b; unsigned short s; } u; u.b = f2b(f); return u.s;
}
static __device__ __forceinline__ unsigned int pack2(float lo, float hi){
  return (unsigned int)bfbits(lo) | ((unsigned int)bfbits(hi) << 16);
}

static __device__ __forceinline__ float redsum32(float t){
  #pragma unroll
  for (int o = 16; o > 0; o >>= 1) t += __shfl_xor(t, o, 32);
  return t;
}
static __device__ __forceinline__ float redmax32(float t){
  #pragma unroll
  for (int o = 16; o > 0; o >>= 1) t = fmaxf(t, __shfl_xor(t, o, 32));
  return t;
}

// GRU fused helper for the tiny readout kernel (32 lanes = one row)
static __device__ __forceinline__ float gru_relu(float hv, float xv, int c,
    const float* __restrict__ wih, const float* __restrict__ whh,
    const float* __restrict__ bih, const float* __restrict__ bhh){
  float gr = bih[c], gz = bih[32+c], gn = bih[64+c];
  float hr = bhh[c], hz = bhh[32+c], hn = bhh[64+c];
  #pragma unroll 8
  for (int k = 0; k < 32; k++){
    float hk = __shfl(hv, k, 32);
    float xk = __shfl(xv, k, 32);
    gr += hk*wih[(     c)*32 + k];
    gz += hk*wih[(32 + c)*32 + k];
    gn += hk*wih[(64 + c)*32 + k];
    hr += xk*whh[(     c)*32 + k];
    hz += xk*whh[(32 + c)*32 + k];
    hn += xk*whh[(64 + c)*32 + k];
  }
  float r = sigm(gr + hr), z = sigm(gz + hz);
  float nn2 = tanh_fast(gn + r*hn);
  return fmaxf((1.f - z)*nn2 + z*xv, 0.f);
}

__global__ __launch_bounds__(THREADS) void k_filli(int* __restrict__ p, int v, int n){
  int i = blockIdx.x*THREADS + threadIdx.x;
  if (i < n) p[i] = v;
}

// ================= FRONT mega-kernel: embed (MFMA) ∥ histrank ∥ gptr ==========
#define FB_EMBED 512
#define FB_HIST  8192
#define FB_GPTR  1024

__global__ __launch_bounds__(THREADS) void k_front(
    const float* __restrict__ xin, const float* __restrict__ lw, const float* __restrict__ lb,
    const float* __restrict__ w1, const float* __restrict__ w2,
    const float* __restrict__ attr_r, float* __restrict__ X,
    bf16* __restrict__ u, bf16* __restrict__ v, float* __restrict__ nr,
    const int* __restrict__ ei, int* __restrict__ hist, int* __restrict__ rank,
    const int* __restrict__ batch, int* __restrict__ gptr){
  __shared__ float ol[4][16][33];
  int bid = blockIdx.x;
  if (bid < FB_EMBED){
    int wid  = bid*4 + (threadIdx.x >> 6);
    int wv   = threadIdx.x >> 6;
    int lane = threadIdx.x & 63;
    int cl = lane & 15;
    int kb = lane >> 4;
    short8v BL[2][2], BU[2], BV[2];
    #pragma unroll
    for (int g = 0; g < 2; g++){
      #pragma unroll
      for (int kc = 0; kc < 2; kc++){
        short8v t;
        #pragma unroll
        for (int j = 0; j < 8; j++){
          int k = kc*32 + kb*8 + j;
          t[j] = (k < 54) ? (short)bfbits(lw[(size_t)(g*16+cl)*54 + k]) : (short)0;
        }
        BL[g][kc] = t;
      }
      short8v tu, tv;
      #pragma unroll
      for (int j = 0; j < 8; j++){
        tu[j] = (short)bfbits(w1[(size_t)(g*16+cl)*33 + kb*8 + j]);
        tv[j] = (short)bfbits(w2[(size_t)(g*16+cl)*32 + kb*8 + j]);
      }
      BU[g] = tu; BV[g] = tv;
    }
    float bb0 = lb[cl], bb1 = lb[16+cl];
    float ar0 = attr_r[cl], ar1 = attr_r[16+cl];
    f32x4 zero; zero[0]=0.f; zero[1]=0.f; zero[2]=0.f; zero[3]=0.f;

    for (int t = 0; t < 8; t++){
      int nb = (wid*8 + t)*16;
      const float* xrow = xin + (size_t)(nb + cl)*54;
      short8v Ax0, Ax1;
      const float2* x2 = (const float2*)(xrow + kb*8);
      #pragma unroll
      for (int jj = 0; jj < 4; jj++){
        float2 tvv = x2[jj];
        Ax0[2*jj]   = (short)bfbits(tvv.x);
        Ax0[2*jj+1] = (short)bfbits(tvv.y);
      }
      #pragma unroll
      for (int j = 0; j < 8; j++){
        int k = 32 + kb*8 + j;
        Ax1[j] = (k < 54) ? (short)bfbits(xrow[k]) : (short)0;
      }
      f32x4 a0, a1;
      #pragma unroll
      for (int q = 0; q < 4; q++){ a0[q] = bb0; a1[q] = bb1; }
      f32x4 d0 = __builtin_amdgcn_mfma_f32_16x16x32_bf16(Ax0, BL[0][0], a0, 0, 0, 0);
      d0 = __builtin_amdgcn_mfma_f32_16x16x32_bf16(Ax1, BL[0][1], d0, 0, 0, 0);
      f32x4 d1 = __builtin_amdgcn_mfma_f32_16x16x32_bf16(Ax0, BL[1][0], a1, 0, 0, 0);
      d1 = __builtin_amdgcn_mfma_f32_16x16x32_bf16(Ax1, BL[1][1], d1, 0, 0, 0);
      #pragma unroll
      for (int r = 0; r < 4; r++){ d0[r] = lrelu(d0[r]); d1[r] = lrelu(d1[r]); }
      #pragma unroll
      for (int r = 0; r < 4; r++){
        int node = nb + kb*4 + r;
        float* srow = X + (size_t)node*32;
        srow[cl]      = d0[r];
        srow[16 + cl] = d1[r];
        ol[wv][kb*4 + r][cl]      = d0[r];
        ol[wv][kb*4 + r][16 + cl] = d1[r];
      }
      #pragma unroll
      for (int r = 0; r < 4; r++){
        float vsum = d0[r]*ar0 + d1[r]*ar1;
        vsum += __shfl_xor(vsum, 1, 16);
        vsum += __shfl_xor(vsum, 2, 16);
        vsum += __shfl_xor(vsum, 4, 16);
        vsum += __shfl_xor(vsum, 8, 16);
        if (cl == 0) nr[nb + kb*4 + r] = vsum;
      }
      __syncthreads();
      short8v Ao;
      #pragma unroll
      for (int j = 0; j < 8; j++) Ao[j] = (short)bfbits(ol[wv][cl][kb*8 + j]);
      f32x4 u0 = __builtin_amdgcn_mfma_f32_16x16x32_bf16(Ao, BU[0], zero, 0, 0, 0);
      f32x4 u1 = __builtin_amdgcn_mfma_f32_16x16x32_bf16(Ao, BU[1], zero, 0, 0, 0);
      f32x4 v0 = __builtin_amdgcn_mfma_f32_16x16x32_bf16(Ao, BV[0], zero, 0, 0, 0);
      f32x4 v1 = __builtin_amdgcn_mfma_f32_16x16x32_bf16(Ao, BV[1], zero, 0, 0, 0);
      #pragma unroll
      for (int r = 0; r < 4; r++){
        int node = nb + kb*4 + r;
        bf16* ur = u + (size_t)node*32;
        bf16* vr = v + (size_t)node*32;
        ur[cl]      = f2b(u0[r]);
        ur[16 + cl] = f2b(u1[r]);
        vr[cl]      = f2b(v0[r]);
        vr[16 + cl] = f2b(v1[r]);
      }
      __syncthreads();
    }
  } else if (bid < FB_EMBED + FB_HIST){
    int e = (bid - FB_EMBED)*THREADS + threadIdx.x;
    rank[e] = atomicAdd(hist + ei[NE + e], 1);
  } else {
    int n = (bid - FB_EMBED - FB_HIST)*THREADS + threadIdx.x;
    int bc = batch[n];
    if (n == 0){ for (int g = 0; g <= bc; g++) gptr[g] = 0; }
    else {
      int pb = batch[n-1];
      if (pb != bc) for (int g = pb+1; g <= bc; g++) gptr[g] = n;
    }
    if (n == NN-1){ for (int g = bc+1; g <= NG; g++) gptr[g] = NN; }
  }
}

// ---------------- scans ----------------
// scan1: per-block exclusive partials -> rp1, block totals -> btot
__global__ __launch_bounds__(THREADS) void k_scan1(const int* __restrict__ hist,
    int* __restrict__ rp1, int* __restrict__ btot){
  __shared__ int sh[THREADS];
  int i = blockIdx.x*THREADS + threadIdx.x;
  int v = hist[i];
  sh[threadIdx.x] = v; __syncthreads();
  #pragma unroll
  for (int off = 1; off < THREADS; off <<= 1){
    int t = (threadIdx.x >= off) ? sh[threadIdx.x - off] : 0;
    __syncthreads(); sh[threadIdx.x] += t; __syncthreads();
  }
  rp1[i] = sh[threadIdx.x] - v;
  if (threadIdx.x == THREADS-1) btot[blockIdx.x] = sh[THREADS-1];
}

__global__ __launch_bounds__(1024) void k_scan2(int* __restrict__ btot){
  __shared__ int sh[1024];
  int i = threadIdx.x;
  int v = btot[i];
  sh[i] = v; __syncthreads();
  for (int off = 1; off < 1024; off <<= 1){
    int t = (i >= off) ? sh[i - off] : 0;
    __syncthreads(); sh[i] += t; __syncthreads();
  }
  btot[i] = sh[i] - v;  // exclusive
}

// ======== MID mega-kernel: scan3 (final rowptr) ∥ atomic-free place ==========
#define MB_SCAN 1024

__global__ __launch_bounds__(THREADS) void k_mid(const int* __restrict__ rp1,
    const int* __restrict__ btot, int* __restrict__ rowptr,
    const int* __restrict__ ei, const float* __restrict__ ea,
    const int* __restrict__ rank, int2* __restrict__ epk){
  int bid = blockIdx.x;
  if (bid < MB_SCAN){
    int i = bid*THREADS + threadIdx.x;
    rowptr[i] = rp1[i] + btot[i >> 8];
    if (i == 0) rowptr[NN] = NE;
  } else {
    int e = (bid - MB_SCAN)*THREADS + threadIdx.x;
    int d = ei[NE + e];
    int pos = rp1[d] + btot[d >> 8] + rank[e];
    epk[pos] = make_int2(ei[e], __float_as_int(ea[e]));
  }
}

// ---- GRU via MFMA + fused att precompute (xt = Xnew@attW^T, s1/s2 dots) ----
__global__ __launch_bounds__(THREADS) void k_gru_att(const bf16* __restrict__ HV,
    float* __restrict__ S,
    const float* __restrict__ wih, const float* __restrict__ whh,
    const float* __restrict__ bih, const float* __restrict__ bhh,
    const float* __restrict__ attW, const float* __restrict__ att1,
    const float* __restrict__ att2,
    bf16* __restrict__ xt, float* __restrict__ s1, float* __restrict__ s2){
  __shared__ float ol[4][16][33];
  int wid  = (blockIdx.x*THREADS + threadIdx.x) >> 6;
  int wv   = threadIdx.x >> 6;
  int lane = threadIdx.x & 63;
  int cl = lane & 15;
  int kb = lane >> 4;
  short8v BW[12], BT[2];
  #pragma unroll
  for (int g = 0; g < 6; g++){
    const float* wr = wih + (size_t)(g*16 + cl)*32 + kb*8;
    const float* vr = whh + (size_t)(g*16 + cl)*32 + kb*8;
    short8v bw, bv;
    #pragma unroll
    for (int j = 0; j < 8; j++){ bw[j] = (short)bfbits(wr[j]); bv[j] = (short)bfbits(vr[j]); }
    BW[g] = bw; BW[6+g] = bv;
  }
  #pragma unroll
  for (int g = 0; g < 2; g++){
    short8v bt;
    #pragma unroll
    for (int j = 0; j < 8; j++) bt[j] = (short)bfbits(attW[(size_t)(g*16+cl)*32 + kb*8 + j]);
    BT[g] = bt;
  }
  float bI[6], bH[6];
  #pragma unroll
  for (int g = 0; g < 6; g++){ bI[g] = bih[g*16 + cl]; bH[g] = bhh[g*16 + cl]; }
  float a1c0 = att1[cl], a1c1 = att1[16+cl];
  float a2c0 = att2 ? att2[cl] : 0.f, a2c1 = att2 ? att2[16+cl] : 0.f;
  f32x4 zero; zero[0]=0.f; zero[1]=0.f; zero[2]=0.f; zero[3]=0.f;

  for (int t = 0; t < 8; t++){
    int nb = (wid*8 + t) * 16;
    short8v Ah = *(const short8v*)(HV + (size_t)(nb + cl)*32 + kb*8);
    const float* xr = S + (size_t)(nb + cl)*32 + kb*8;
    short8v Ax;
    #pragma unroll
    for (int j = 0; j < 8; j++) Ax[j] = (short)bfbits(xr[j]);
    f32x4 gi[6], gh[6];
    #pragma unroll
    for (int g = 0; g < 6; g++){
      f32x4 a, b;
      #pragma unroll
      for (int q = 0; q < 4; q++){ a[q] = bI[g]; b[q] = bH[g]; }
      gi[g] = __builtin_amdgcn_mfma_f32_16x16x32_bf16(Ah, BW[g],   a, 0, 0, 0);
      gh[g] = __builtin_amdgcn_mfma_f32_16x16x32_bf16(Ax, BW[6+g], b, 0, 0, 0);
    }
    #pragma unroll
    for (int r = 0; r < 4; r++){
      int node = nb + kb*4 + r;
      float* srow = S + (size_t)node*32;
      float x0 = srow[cl], x1 = srow[16 + cl];
      float r0 = sigm(gi[0][r] + gh[0][r]);
      float z0 = sigm(gi[2][r] + gh[2][r]);
      float n0 = tanh_fast(gi[4][r] + r0*gh[4][r]);
      float r1 = sigm(gi[1][r] + gh[1][r]);
      float z1 = sigm(gi[3][r] + gh[3][r]);
      float n1 = tanh_fast(gi[5][r] + r1*gh[5][r]);
      float o0 = fmaxf((1.f - z0)*n0 + z0*x0, 0.f);
      float o1 = fmaxf((1.f - z1)*n1 + z1*x1, 0.f);
      srow[cl]      = o0;
      srow[16 + cl] = o1;
      ol[wv][kb*4 + r][cl]      = o0;
      ol[wv][kb*4 + r][16 + cl] = o1;
    }
    __syncthreads();
    short8v Ao;
    #pragma unroll
    for (int j = 0; j < 8; j++) Ao[j] = (short)bfbits(ol[wv][cl][kb*8 + j]);
    f32x4 t0 = __builtin_amdgcn_mfma_f32_16x16x32_bf16(Ao, BT[0], zero, 0, 0, 0);
    f32x4 t1 = __builtin_amdgcn_mfma_f32_16x16x32_bf16(Ao, BT[1], zero, 0, 0, 0);
    #pragma unroll
    for (int r = 0; r < 4; r++){
      int node = nb + kb*4 + r;
      bf16* xrow = xt + (size_t)node*32;
      xrow[cl]      = f2b(t0[r]);
      xrow[16 + cl] = f2b(t1[r]);
      float p1 = t0[r]*a1c0 + t1[r]*a1c1;
      p1 += __shfl_xor(p1, 1, 16);
      p1 += __shfl_xor(p1, 2, 16);
      p1 += __shfl_xor(p1, 4, 16);
      p1 += __shfl_xor(p1, 8, 16);
      if (cl == 0) s1[node] = p1;
      if (att2){
        float p2 = t0[r]*a2c0 + t1[r]*a2c1;
        p2 += __shfl_xor(p2, 1, 16);
        p2 += __shfl_xor(p2, 2, 16);
        p2 += __shfl_xor(p2, 4, 16);
        p2 += __shfl_xor(p2, 8, 16);
        if (cl == 0) s2[node] = p2;
      }
    }
    __syncthreads();
  }
}

// ---------------- edge-parallel logits (GATEConv only) ----------------
__global__ __launch_bounds__(THREADS) void k_elog1(const int2* __restrict__ epk,
    const bf16* __restrict__ U,
    const float* __restrict__ w1 /*32x33*/, const float* __restrict__ attl,
    float* __restrict__ elog){
  int q  = threadIdx.x & 3;
  int lg = threadIdx.x >> 2;
  float wc[8], at[8];
  #pragma unroll
  for (int j = 0; j < 8; j++){
    wc[j] = w1[(q*8 + j)*33 + 32];
    at[j] = attl[q*8 + j];
  }
  int base = blockIdx.x * 512;
  #pragma unroll 2
  for (int i = 0; i < 8; i++){
    int p = base + i*64 + lg;
    int2 pk = epk[p];
    int si = pk.x;
    float a = __int_as_float(pk.y);
    short8v u8 = *(const short8v*)(U + (size_t)si*32 + q*8);
    float t = 0.f;
    #pragma unroll
    for (int j = 0; j < 8; j++) t += at[j]*lrelu(s2f(u8[j]) + a*wc[j]);
    t += __shfl_xor(t, 1, 4);
    t += __shfl_xor(t, 2, 4);
    if (q == 0) elog[p] = t;
  }
}

// ---- conv v2: max pass, then fused weight+sum+gather pass; one exp per edge ----
__global__ __launch_bounds__(THREADS) void k_conv(const int* __restrict__ rowptr,
    const int2* __restrict__ epk, const float* __restrict__ lg,
    const float* __restrict__ alsrc, const float* __restrict__ term,
    const bf16* __restrict__ ROWS, const float* __restrict__ bias,
    bf16* __restrict__ HV){
  int node = blockIdx.x*(THREADS/32) + (threadIdx.x >> 5);
  int c32 = threadIdx.x & 31;
  int ws = rowptr[node], we = rowptr[node+1];
  float tv = term[node];
  float m = -INFINITY;
  for (int p0 = ws; p0 < we; p0 += 32){
    int p = p0 + c32;
    bool ok = p < we;
    int pc = ok ? p : ws;
    float sc = lg ? lg[pc] : alsrc[epk[pc].x];
    float l = ok ? lrelu(sc + tv) : -INFINITY;
    m = fmaxf(m, redmax32(l));
  }
  int eg = c32 >> 2, cb = c32 & 3;
  float s = 0.f;
  float acc[8];
  #pragma unroll
  for (int j = 0; j < 8; j++) acc[j] = 0.f;
  for (int p0 = ws; p0 < we; p0 += 32){
    int p = p0 + c32;
    bool ok = p < we;
    int pc = ok ? p : ws;
    int siA = epk[pc].x;
    float sc = lg ? lg[pc] : alsrc[siA];
    float wme = ok ? __expf(lrelu(sc + tv) - m) : 0.f;
    s += redsum32(wme);
    #pragma unroll
    for (int s8 = 0; s8 < 32; s8 += 8){
      if (p0 + s8 >= we) break;
      float w = __shfl(wme, s8 + eg, 32);
      int si  = __shfl(siA, s8 + eg, 32);
      short8v r8 = *(const short8v*)(ROWS + (size_t)si*32 + cb*8);
      #pragma unroll
      for (int j = 0; j < 8; j++) acc[j] += s2f(r8[j]) * w;
    }
  }
  float inv = 1.f/(s + 1e-16f);
  #pragma unroll
  for (int j = 0; j < 8; j++){
    acc[j] += __shfl_xor(acc[j], 4, 32);
    acc[j] += __shfl_xor(acc[j], 8, 32);
    acc[j] += __shfl_xor(acc[j], 16, 32);
  }
  if (eg == 0){
    unsigned int o[4];
    #pragma unroll
    for (int j2 = 0; j2 < 4; j2++){
      float h0 = eluf(acc[2*j2  ]*inv + bias[cb*8 + 2*j2  ]);
      float h1 = eluf(acc[2*j2+1]*inv + bias[cb*8 + 2*j2+1]);
      o[j2] = pack2(h0, h1);
    }
    *(uint4*)(HV + (size_t)node*32 + cb*8) = make_uint4(o[0], o[1], o[2], o[3]);
  }
}

// ============== TAIL mega-kernel: rsum ∥ q ===================================
#define TB_RSUM 1024

__global__ __launch_bounds__(THREADS) void k_tail(const int* __restrict__ gptr,
    const float* __restrict__ X, float* __restrict__ gout,
    const float* __restrict__ mw, const float* __restrict__ mattd,
    float* __restrict__ q){
  int bid = blockIdx.x;
  if (bid < TB_RSUM){
    int g = bid*(THREADS/32) + (threadIdx.x >> 5);
    int c = threadIdx.x & 31;
    int gs = gptr[g], ge = gptr[g+1];
    float acc = 0.f;
    for (int n = gs; n < ge; n++) acc += X[(size_t)n*32 + c];
    gout[(size_t)g*32 + c] = fmaxf(acc, 0.f);
  } else {
    int k = threadIdx.x;
    if (k < 32){
      float acc = 0.f;
      #pragma unroll
      for (int c = 0; c < 32; c++) acc += mattd[c] * mw[c*32 + k];
      q[k] = acc;
    }
  }
}

// one readout timestep: softmax over nodes of graph + weighted sum + GRU3
__global__ __launch_bounds__(THREADS) void k_rstep(const int* __restrict__ gptr,
    const float* __restrict__ anode, const bf16* __restrict__ XS,
    const float* __restrict__ q, const float* __restrict__ mbias,
    float* __restrict__ gout,
    const float* __restrict__ wih, const float* __restrict__ whh,
    const float* __restrict__ bih, const float* __restrict__ bhh){
  int g = blockIdx.x*(THREADS/32) + (threadIdx.x >> 5);
  int c = threadIdx.x & 31;
  float orow = gout[(size_t)g*32 + c];
  float ag = redsum32(orow * q[c]);
  int gs = gptr[g], ge = gptr[g+1];
  float m = -INFINITY, s = 0.f;
  for (int p0 = gs; p0 < ge; p0 += 32){
    int p = p0 + c;
    bool ok = p < ge;
    float lg = ok ? lrelu(anode[p] + ag) : -INFINITY;
    float cm = redmax32(lg);
    float mn = fmaxf(m, cm);
    float e = ok ? __expf(lg - mn) : 0.f;
    float cs = redsum32(e);
    s = s*__expf(m - mn) + cs;
    m = mn;
  }
  float inv = 1.f/(s + 1e-16f);
  float acc = 0.f;
  int n = gs;
  for (; n + 4 <= ge; n += 4){
    float e0 = __expf(lrelu(anode[n]   + ag) - m);
    float e1 = __expf(lrelu(anode[n+1] + ag) - m);
    float e2 = __expf(lrelu(anode[n+2] + ag) - m);
    float e3 = __expf(lrelu(anode[n+3] + ag) - m);
    acc += b2f(XS[(size_t)(n  )*32 + c])*e0 + b2f(XS[(size_t)(n+1)*32 + c])*e1
         + b2f(XS[(size_t)(n+2)*32 + c])*e2 + b2f(XS[(size_t)(n+3)*32 + c])*e3;
  }
  for (; n < ge; n++)
    acc += b2f(XS[(size_t)n*32 + c]) * __expf(lrelu(anode[n] + ag) - m);
  acc *= inv;
  float hv = eluf(acc + mbias[c]);
  gout[(size_t)g*32 + c] = gru_relu(hv, orow, c, wih, whh, bih, bhh);
}

// y = mish(out @ lin2^T + b)
__global__ __launch_bounds__(THREADS) void k_final(const float* __restrict__ out32,
    const float* __restrict__ w /*64x32*/, const float* __restrict__ b,
    float* __restrict__ y){
  int gid = blockIdx.x*THREADS + threadIdx.x;
  int g = gid >> 6, oc = gid & 63;
  const float* orow = out32 + (size_t)g*32;
  const float* wr = w + oc*32;
  float acc = b[oc];
  #pragma unroll
  for (int k = 0; k < 32; k++) acc += orow[k]*wr[k];
  float sp = fmaxf(acc, 0.f) + log1pf(expf(-fabsf(acc)));  // keep precise (final output)
  y[(size_t)g*64 + oc] = acc * tanhf(sp);
}

extern "C" void kernel_launch(void* const* d_in, const int* in_sizes, int n_in,
                              void* d_out, int out_size, void* d_ws, size_t ws_size,
                              hipStream_t stream){
  const float* x_in     = (const float*)d_in[0];
  const float* ea       = (const float*)d_in[1];
  const int*   ei       = (const int*)  d_in[2];
  const int*   batch    = (const int*)  d_in[3];
  const float* lin1_w   = (const float*)d_in[4];
  const float* lin1_b   = (const float*)d_in[5];
  const float* g_lin1_w = (const float*)d_in[6];
  const float* g_lin2_w = (const float*)d_in[7];
  const float* g_att_l  = (const float*)d_in[8];
  const float* g_att_r  = (const float*)d_in[9];
  const float* g_bias   = (const float*)d_in[10];
  const float* gru1_wih = (const float*)d_in[11];
  const float* gru1_whh = (const float*)d_in[12];
  const float* gru1_bih = (const float*)d_in[13];
  const float* gru1_bhh = (const float*)d_in[14];
  const float* a_lin_w  = (const float*)d_in[15];
  const float* a_att_src= (const float*)d_in[16];
  const float* a_att_dst= (const float*)d_in[17];
  const float* a_bias   = (const float*)d_in[18];
  const float* gru2_wih = (const float*)d_in[19];
  const float* gru2_whh = (const float*)d_in[20];
  const float* gru2_bih = (const float*)d_in[21];
  const float* gru2_bhh = (const float*)d_in[22];
  const float* m_lin_w  = (const float*)d_in[23];
  const float* m_att_src= (const float*)d_in[24];
  const float* m_att_dst= (const float*)d_in[25];
  const float* m_bias   = (const float*)d_in[26];
  const float* gru3_wih = (const float*)d_in[27];
  const float* gru3_whh = (const float*)d_in[28];
  const float* gru3_bih = (const float*)d_in[29];
  const float* gru3_bhh = (const float*)d_in[30];
  const float* lin2_w   = (const float*)d_in[31];
  const float* lin2_b   = (const float*)d_in[32];

  float* W = (float*)d_ws;
  float* X     = W;                      // NN*32 f32
  bf16*  BA    = (bf16*)(W + 8388608);   // NN*32 bf16 : u / h1 / xt / xs
  bf16*  BB    = (bf16*)(W + 12582912);  // NN*32 bf16 : v / h2
  int2*  EPK   = (int2*) (W + 16777216); // NE x (src, ea-bits)
  float* ELOG  = W + 20971520;           // NE raw GATEConv edge scores (first NN ints = RP1 scratch)
  int*   RP1   = (int*)  (W + 20971520); // NN partial scan (aliases ELOG; dead before elog1)
  int*   RANK  = (int*)  (W + 23068672); // NE within-dst ranks
  int*   ROWPTR= (int*)  (W + 25165824); // NN+1 (pad)
  int*   HIST  = (int*)  (W + 25428032); // NN
  int*   BTOT  = (int*)  (W + 25690176); // 1024
  float* NS1   = W + 25691200;           // NN : nr / al / a_node
  float* NS2   = W + 25953344;           // NN : ar
  int*   GPTR  = (int*)  (W + 26215488); // NG+1 (pad)
  float* GOUT  = W + 26223744;           // NG*32
  float* Q     = W + 26485888;           // 32

  dim3 b(THREADS);
  const int gNode  = NN/THREADS;        // 1024
  const int gElog1 = NE/512;            // 4096
  const int gNode32= NN/(THREADS/32);   // 32768
  const int gG32   = NG/(THREADS/32);   // 1024
  const int gMFMA  = NN/(16*8*4);       // 512

  // zero HIST (must precede k_front's histrank section)
  k_filli<<<gNode, b, 0, stream>>>(HIST, 0, NN);

  // FRONT: embed (MFMA) ∥ histrank (atomics) ∥ gptr
  k_front<<<FB_EMBED + FB_HIST + FB_GPTR, b, 0, stream>>>(
      x_in, lin1_w, lin1_b, g_lin1_w, g_lin2_w, g_att_r, X, BA, BB, NS1,
      ei, HIST, RANK, batch, GPTR);

  // scans; MID: final rowptr ∥ atomic-free place (from partials)
  k_scan1<<<gNode, b, 0, stream>>>(HIST, RP1, BTOT);
  k_scan2<<<1, 1024, 0, stream>>>(BTOT);
  k_mid<<<MB_SCAN + NE/THREADS, b, 0, stream>>>(RP1, BTOT, ROWPTR, ei, ea, RANK, EPK);

  // GATEConv + GRU1 (fused att precompute for GATConv: xt->BA, al->NS1, ar->NS2)
  k_elog1<<<gElog1, b, 0, stream>>>(EPK, BA, g_lin1_w, g_att_l, ELOG);
  k_conv<<<gNode32, b, 0, stream>>>(ROWPTR, EPK, ELOG, nullptr, NS1, BB, g_bias, BA);
  k_gru_att<<<gMFMA, b, 0, stream>>>(BA, X, gru1_wih, gru1_whh, gru1_bih, gru1_bhh,
      a_lin_w, a_att_src, a_att_dst, BA, NS1, NS2);

  // GATConv + GRU2 (fused readout precompute: xs->BA, a_node->NS1)
  k_conv<<<gNode32, b, 0, stream>>>(ROWPTR, EPK, nullptr, NS1, NS2, BA, a_bias, BB);
  k_gru_att<<<gMFMA, b, 0, stream>>>(BB, X, gru2_wih, gru2_whh, gru2_bih, gru2_bhh,
      m_lin_w, m_att_src, nullptr, BA, NS1, nullptr);

  // TAIL: rsum ∥ q
  k_tail<<<TB_RSUM + 1, b, 0, stream>>>(GPTR, X, GOUT, m_lin_w, m_att_dst, Q);

  for (int t = 0; t < 2; t++){
    k_rstep<<<gG32, b, 0, stream>>>(GPTR, NS1, BA, Q, m_bias, GOUT,
        gru3_wih, gru3_whh, gru3_bih, gru3_bhh);
  }

  k_final<<<(NG*64)/THREADS, b, 0, stream>>>(GOUT, lin2_w, lin2_b, (float*)d_out);
}

// Round 16
// 469.781 us; speedup vs baseline: 1.7669x; 1.0350x over previous
//
#include <hip/hip_runtime.h>
#include <hip/hip_bf16.h>
#include <math.h>

#define NN 262144
#define NE 2097152
#define NG 8192
#define THREADS 256

typedef __hip_bfloat16 bf16;
typedef __attribute__((ext_vector_type(8))) short short8v;   // 8 bf16 (4 VGPRs)
typedef __attribute__((ext_vector_type(4))) float f32x4;

static __device__ __forceinline__ float lrelu(float x){ return x > 0.f ? x : 0.01f*x; }
static __device__ __forceinline__ float eluf(float x){ return x > 0.f ? x : __expf(x) - 1.f; }
static __device__ __forceinline__ float sigm(float x){ return 1.f/(1.f + __expf(-x)); }
static __device__ __forceinline__ float tanh_fast(float x){
  float e = __expf(2.f*x); return 1.f - 2.f/(e + 1.f);
}
static __device__ __forceinline__ float b2f(bf16 v){ return __bfloat162float(v); }
static __device__ __forceinline__ bf16 f2b(float v){ return __float2bfloat16(v); }
// bit-reinterpret a raw bf16 (held in a short) to float — NEVER value-convert!
static __device__ __forceinline__ float s2f(short s){
  return __uint_as_float(((unsigned int)(unsigned short)s) << 16);
}

static __device__ __forceinline__ unsigned short bfbits(float f){
  union { bf16 b; unsigned short s; } u; u.b = f2b(f); return u.s;
}
static __device__ __forceinline__ unsigned int pack2(float lo, float hi){
  return (unsigned int)bfbits(lo) | ((unsigned int)bfbits(hi) << 16);
}

static __device__ __forceinline__ float redsum32(float t){
  #pragma unroll
  for (int o = 16; o > 0; o >>= 1) t += __shfl_xor(t, o, 32);
  return t;
}

// GRU fused helper for the tiny readout kernel (32 lanes = one row)
static __device__ __forceinline__ float gru_relu(float hv, float xv, int c,
    const float* __restrict__ wih, const float* __restrict__ whh,
    const float* __restrict__ bih, const float* __restrict__ bhh){
  float gr = bih[c], gz = bih[32+c], gn = bih[64+c];
  float hr = bhh[c], hz = bhh[32+c], hn = bhh[64+c];
  #pragma unroll 8
  for (int k = 0; k < 32; k++){
    float hk = __shfl(hv, k, 32);
    float xk = __shfl(xv, k, 32);
    gr += hk*wih[(     c)*32 + k];
    gz += hk*wih[(32 + c)*32 + k];
    gn += hk*wih[(64 + c)*32 + k];
    hr += xk*whh[(     c)*32 + k];
    hz += xk*whh[(32 + c)*32 + k];
    hn += xk*whh[(64 + c)*32 + k];
  }
  float r = sigm(gr + hr), z = sigm(gz + hz);
  float nn2 = tanh_fast(gn + r*hn);
  return fmaxf((1.f - z)*nn2 + z*xv, 0.f);
}

__global__ __launch_bounds__(THREADS) void k_filli(int* __restrict__ p, int v, int n){
  int i = blockIdx.x*THREADS + threadIdx.x;
  if (i < n) p[i] = v;
}

// ================= FRONT mega-kernel: embed (MFMA) ∥ histrank ∥ gptr ==========
#define FB_EMBED 512
#define FB_HIST  8192
#define FB_GPTR  1024

__global__ __launch_bounds__(THREADS) void k_front(
    const float* __restrict__ xin, const float* __restrict__ lw, const float* __restrict__ lb,
    const float* __restrict__ w1, const float* __restrict__ w2,
    const float* __restrict__ attr_r, float* __restrict__ X,
    bf16* __restrict__ u, bf16* __restrict__ v, float* __restrict__ nr,
    const int* __restrict__ ei, int* __restrict__ hist, int* __restrict__ rank,
    const int* __restrict__ batch, int* __restrict__ gptr){
  __shared__ float ol[4][16][33];
  int bid = blockIdx.x;
  if (bid < FB_EMBED){
    int wid  = bid*4 + (threadIdx.x >> 6);
    int wv   = threadIdx.x >> 6;
    int lane = threadIdx.x & 63;
    int cl = lane & 15;
    int kb = lane >> 4;
    short8v BL[2][2], BU[2], BV[2];
    #pragma unroll
    for (int g = 0; g < 2; g++){
      #pragma unroll
      for (int kc = 0; kc < 2; kc++){
        short8v t;
        #pragma unroll
        for (int j = 0; j < 8; j++){
          int k = kc*32 + kb*8 + j;
          t[j] = (k < 54) ? (short)bfbits(lw[(size_t)(g*16+cl)*54 + k]) : (short)0;
        }
        BL[g][kc] = t;
      }
      short8v tu, tv;
      #pragma unroll
      for (int j = 0; j < 8; j++){
        tu[j] = (short)bfbits(w1[(size_t)(g*16+cl)*33 + kb*8 + j]);
        tv[j] = (short)bfbits(w2[(size_t)(g*16+cl)*32 + kb*8 + j]);
      }
      BU[g] = tu; BV[g] = tv;
    }
    float bb0 = lb[cl], bb1 = lb[16+cl];
    float ar0 = attr_r[cl], ar1 = attr_r[16+cl];
    f32x4 zero; zero[0]=0.f; zero[1]=0.f; zero[2]=0.f; zero[3]=0.f;

    for (int t = 0; t < 8; t++){
      int nb = (wid*8 + t)*16;
      const float* xrow = xin + (size_t)(nb + cl)*54;
      short8v Ax0, Ax1;
      const float2* x2 = (const float2*)(xrow + kb*8);
      #pragma unroll
      for (int jj = 0; jj < 4; jj++){
        float2 tvv = x2[jj];
        Ax0[2*jj]   = (short)bfbits(tvv.x);
        Ax0[2*jj+1] = (short)bfbits(tvv.y);
      }
      #pragma unroll
      for (int j = 0; j < 8; j++){
        int k = 32 + kb*8 + j;
        Ax1[j] = (k < 54) ? (short)bfbits(xrow[k]) : (short)0;
      }
      f32x4 a0, a1;
      #pragma unroll
      for (int q = 0; q < 4; q++){ a0[q] = bb0; a1[q] = bb1; }
      f32x4 d0 = __builtin_amdgcn_mfma_f32_16x16x32_bf16(Ax0, BL[0][0], a0, 0, 0, 0);
      d0 = __builtin_amdgcn_mfma_f32_16x16x32_bf16(Ax1, BL[0][1], d0, 0, 0, 0);
      f32x4 d1 = __builtin_amdgcn_mfma_f32_16x16x32_bf16(Ax0, BL[1][0], a1, 0, 0, 0);
      d1 = __builtin_amdgcn_mfma_f32_16x16x32_bf16(Ax1, BL[1][1], d1, 0, 0, 0);
      #pragma unroll
      for (int r = 0; r < 4; r++){ d0[r] = lrelu(d0[r]); d1[r] = lrelu(d1[r]); }
      #pragma unroll
      for (int r = 0; r < 4; r++){
        int node = nb + kb*4 + r;
        float* srow = X + (size_t)node*32;
        srow[cl]      = d0[r];
        srow[16 + cl] = d1[r];
        ol[wv][kb*4 + r][cl]      = d0[r];
        ol[wv][kb*4 + r][16 + cl] = d1[r];
      }
      #pragma unroll
      for (int r = 0; r < 4; r++){
        float vsum = d0[r]*ar0 + d1[r]*ar1;
        vsum += __shfl_xor(vsum, 1, 16);
        vsum += __shfl_xor(vsum, 2, 16);
        vsum += __shfl_xor(vsum, 4, 16);
        vsum += __shfl_xor(vsum, 8, 16);
        if (cl == 0) nr[nb + kb*4 + r] = vsum;
      }
      __syncthreads();
      short8v Ao;
      #pragma unroll
      for (int j = 0; j < 8; j++) Ao[j] = (short)bfbits(ol[wv][cl][kb*8 + j]);
      f32x4 u0 = __builtin_amdgcn_mfma_f32_16x16x32_bf16(Ao, BU[0], zero, 0, 0, 0);
      f32x4 u1 = __builtin_amdgcn_mfma_f32_16x16x32_bf16(Ao, BU[1], zero, 0, 0, 0);
      f32x4 v0 = __builtin_amdgcn_mfma_f32_16x16x32_bf16(Ao, BV[0], zero, 0, 0, 0);
      f32x4 v1 = __builtin_amdgcn_mfma_f32_16x16x32_bf16(Ao, BV[1], zero, 0, 0, 0);
      #pragma unroll
      for (int r = 0; r < 4; r++){
        int node = nb + kb*4 + r;
        bf16* ur = u + (size_t)node*32;
        bf16* vr = v + (size_t)node*32;
        ur[cl]      = f2b(u0[r]);
        ur[16 + cl] = f2b(u1[r]);
        vr[cl]      = f2b(v0[r]);
        vr[16 + cl] = f2b(v1[r]);
      }
      __syncthreads();
    }
  } else if (bid < FB_EMBED + FB_HIST){
    int e = (bid - FB_EMBED)*THREADS + threadIdx.x;
    rank[e] = atomicAdd(hist + ei[NE + e], 1);
  } else {
    int n = (bid - FB_EMBED - FB_HIST)*THREADS + threadIdx.x;
    int bc = batch[n];
    if (n == 0){ for (int g = 0; g <= bc; g++) gptr[g] = 0; }
    else {
      int pb = batch[n-1];
      if (pb != bc) for (int g = pb+1; g <= bc; g++) gptr[g] = n;
    }
    if (n == NN-1){ for (int g = bc+1; g <= NG; g++) gptr[g] = NN; }
  }
}

// ---------------- scans ----------------
__global__ __launch_bounds__(THREADS) void k_scan1(const int* __restrict__ hist,
    int* __restrict__ rp1, int* __restrict__ btot){
  __shared__ int sh[THREADS];
  int i = blockIdx.x*THREADS + threadIdx.x;
  int v = hist[i];
  sh[threadIdx.x] = v; __syncthreads();
  #pragma unroll
  for (int off = 1; off < THREADS; off <<= 1){
    int t = (threadIdx.x >= off) ? sh[threadIdx.x - off] : 0;
    __syncthreads(); sh[threadIdx.x] += t; __syncthreads();
  }
  rp1[i] = sh[threadIdx.x] - v;
  if (threadIdx.x == THREADS-1) btot[blockIdx.x] = sh[THREADS-1];
}

__global__ __launch_bounds__(1024) void k_scan2(int* __restrict__ btot){
  __shared__ int sh[1024];
  int i = threadIdx.x;
  int v = btot[i];
  sh[i] = v; __syncthreads();
  for (int off = 1; off < 1024; off <<= 1){
    int t = (i >= off) ? sh[i - off] : 0;
    __syncthreads(); sh[i] += t; __syncthreads();
  }
  btot[i] = sh[i] - v;  // exclusive
}

// ======== MID mega-kernel: final rowptr ∥ atomic-free place ==================
#define MB_SCAN 1024

__global__ __launch_bounds__(THREADS) void k_mid(const int* __restrict__ rp1,
    const int* __restrict__ btot, int* __restrict__ rowptr,
    const int* __restrict__ ei, const float* __restrict__ ea,
    const int* __restrict__ rank, int2* __restrict__ epk){
  int bid = blockIdx.x;
  if (bid < MB_SCAN){
    int i = bid*THREADS + threadIdx.x;
    rowptr[i] = rp1[i] + btot[i >> 8];
    if (i == 0) rowptr[NN] = NE;
  } else {
    int e = (bid - MB_SCAN)*THREADS + threadIdx.x;
    int d = ei[NE + e];
    int pos = rp1[d] + btot[d >> 8] + rank[e];
    epk[pos] = make_int2(ei[e], __float_as_int(ea[e]));
  }
}

// ---- GRU via MFMA + fused att precompute ----
__global__ __launch_bounds__(THREADS) void k_gru_att(const bf16* __restrict__ HV,
    float* __restrict__ S,
    const float* __restrict__ wih, const float* __restrict__ whh,
    const float* __restrict__ bih, const float* __restrict__ bhh,
    const float* __restrict__ attW, const float* __restrict__ att1,
    const float* __restrict__ att2,
    bf16* __restrict__ xt, float* __restrict__ s1, float* __restrict__ s2){
  __shared__ float ol[4][16][33];
  int wid  = (blockIdx.x*THREADS + threadIdx.x) >> 6;
  int wv   = threadIdx.x >> 6;
  int lane = threadIdx.x & 63;
  int cl = lane & 15;
  int kb = lane >> 4;
  short8v BW[12], BT[2];
  #pragma unroll
  for (int g = 0; g < 6; g++){
    const float* wr = wih + (size_t)(g*16 + cl)*32 + kb*8;
    const float* vr = whh + (size_t)(g*16 + cl)*32 + kb*8;
    short8v bw, bv;
    #pragma unroll
    for (int j = 0; j < 8; j++){ bw[j] = (short)bfbits(wr[j]); bv[j] = (short)bfbits(vr[j]); }
    BW[g] = bw; BW[6+g] = bv;
  }
  #pragma unroll
  for (int g = 0; g < 2; g++){
    short8v bt;
    #pragma unroll
    for (int j = 0; j < 8; j++) bt[j] = (short)bfbits(attW[(size_t)(g*16+cl)*32 + kb*8 + j]);
    BT[g] = bt;
  }
  float bI[6], bH[6];
  #pragma unroll
  for (int g = 0; g < 6; g++){ bI[g] = bih[g*16 + cl]; bH[g] = bhh[g*16 + cl]; }
  float a1c0 = att1[cl], a1c1 = att1[16+cl];
  float a2c0 = att2 ? att2[cl] : 0.f, a2c1 = att2 ? att2[16+cl] : 0.f;
  f32x4 zero; zero[0]=0.f; zero[1]=0.f; zero[2]=0.f; zero[3]=0.f;

  for (int t = 0; t < 8; t++){
    int nb = (wid*8 + t) * 16;
    short8v Ah = *(const short8v*)(HV + (size_t)(nb + cl)*32 + kb*8);
    const float* xr = S + (size_t)(nb + cl)*32 + kb*8;
    short8v Ax;
    #pragma unroll
    for (int j = 0; j < 8; j++) Ax[j] = (short)bfbits(xr[j]);
    f32x4 gi[6], gh[6];
    #pragma unroll
    for (int g = 0; g < 6; g++){
      f32x4 a, b;
      #pragma unroll
      for (int q = 0; q < 4; q++){ a[q] = bI[g]; b[q] = bH[g]; }
      gi[g] = __builtin_amdgcn_mfma_f32_16x16x32_bf16(Ah, BW[g],   a, 0, 0, 0);
      gh[g] = __builtin_amdgcn_mfma_f32_16x16x32_bf16(Ax, BW[6+g], b, 0, 0, 0);
    }
    #pragma unroll
    for (int r = 0; r < 4; r++){
      int node = nb + kb*4 + r;
      float* srow = S + (size_t)node*32;
      float x0 = srow[cl], x1 = srow[16 + cl];
      float r0 = sigm(gi[0][r] + gh[0][r]);
      float z0 = sigm(gi[2][r] + gh[2][r]);
      float n0 = tanh_fast(gi[4][r] + r0*gh[4][r]);
      float r1 = sigm(gi[1][r] + gh[1][r]);
      float z1 = sigm(gi[3][r] + gh[3][r]);
      float n1 = tanh_fast(gi[5][r] + r1*gh[5][r]);
      float o0 = fmaxf((1.f - z0)*n0 + z0*x0, 0.f);
      float o1 = fmaxf((1.f - z1)*n1 + z1*x1, 0.f);
      srow[cl]      = o0;
      srow[16 + cl] = o1;
      ol[wv][kb*4 + r][cl]      = o0;
      ol[wv][kb*4 + r][16 + cl] = o1;
    }
    __syncthreads();
    short8v Ao;
    #pragma unroll
    for (int j = 0; j < 8; j++) Ao[j] = (short)bfbits(ol[wv][cl][kb*8 + j]);
    f32x4 t0 = __builtin_amdgcn_mfma_f32_16x16x32_bf16(Ao, BT[0], zero, 0, 0, 0);
    f32x4 t1 = __builtin_amdgcn_mfma_f32_16x16x32_bf16(Ao, BT[1], zero, 0, 0, 0);
    #pragma unroll
    for (int r = 0; r < 4; r++){
      int node = nb + kb*4 + r;
      bf16* xrow = xt + (size_t)node*32;
      xrow[cl]      = f2b(t0[r]);
      xrow[16 + cl] = f2b(t1[r]);
      float p1 = t0[r]*a1c0 + t1[r]*a1c1;
      p1 += __shfl_xor(p1, 1, 16);
      p1 += __shfl_xor(p1, 2, 16);
      p1 += __shfl_xor(p1, 4, 16);
      p1 += __shfl_xor(p1, 8, 16);
      if (cl == 0) s1[node] = p1;
      if (att2){
        float p2 = t0[r]*a2c0 + t1[r]*a2c1;
        p2 += __shfl_xor(p2, 1, 16);
        p2 += __shfl_xor(p2, 2, 16);
        p2 += __shfl_xor(p2, 4, 16);
        p2 += __shfl_xor(p2, 8, 16);
        if (cl == 0) s2[node] = p2;
      }
    }
    __syncthreads();
  }
}

// ---- conv v3: no-max softmax (logits bounded); per-edge weight computed once.
// Score: GATEConv dot from U row (if U != null) else alsrc[src]; + term[node], lrelu.
__global__ __launch_bounds__(THREADS) void k_conv(const int* __restrict__ rowptr,
    const int2* __restrict__ epk, const bf16* __restrict__ U,
    const float* __restrict__ w1 /*32x33*/, const float* __restrict__ attl,
    const float* __restrict__ alsrc, const float* __restrict__ term,
    const bf16* __restrict__ ROWS, const float* __restrict__ bias,
    bf16* __restrict__ HV){
  int node = blockIdx.x*(THREADS/32) + (threadIdx.x >> 5);
  int c32 = threadIdx.x & 31;
  int ws = rowptr[node], we = rowptr[node+1];
  float tv = term[node];
  float wc[32], at[32];
  if (U){
    #pragma unroll
    for (int j = 0; j < 32; j++){ wc[j] = w1[j*33 + 32]; at[j] = attl[j]; }
  }
  int eg = c32 >> 2, cb = c32 & 3;
  float s = 0.f;
  float acc[8];
  #pragma unroll
  for (int j = 0; j < 8; j++) acc[j] = 0.f;
  for (int p0 = ws; p0 < we; p0 += 32){
    int p = p0 + c32;
    bool ok = p < we;
    int pc = ok ? p : ws;
    int2 pk = epk[pc];
    int siA = pk.x;
    float sc;
    if (U){
      float a = __int_as_float(pk.y);
      const short8v* ur = (const short8v*)(U + (size_t)siA*32);
      sc = 0.f;
      #pragma unroll
      for (int q = 0; q < 4; q++){
        short8v u8 = ur[q];
        #pragma unroll
        for (int j = 0; j < 8; j++)
          sc += at[q*8+j]*lrelu(s2f(u8[j]) + a*wc[q*8+j]);
      }
    } else {
      sc = alsrc[siA];
    }
    float wme = ok ? __expf(lrelu(sc + tv)) : 0.f;
    s += redsum32(wme);
    #pragma unroll
    for (int s8 = 0; s8 < 32; s8 += 8){
      if (p0 + s8 >= we) break;
      float w = __shfl(wme, s8 + eg, 32);
      int si  = __shfl(siA, s8 + eg, 32);
      short8v r8 = *(const short8v*)(ROWS + (size_t)si*32 + cb*8);
      #pragma unroll
      for (int j = 0; j < 8; j++) acc[j] += s2f(r8[j]) * w;
    }
  }
  float inv = 1.f/(s + 1e-16f);
  #pragma unroll
  for (int j = 0; j < 8; j++){
    acc[j] += __shfl_xor(acc[j], 4, 32);
    acc[j] += __shfl_xor(acc[j], 8, 32);
    acc[j] += __shfl_xor(acc[j], 16, 32);
  }
  if (eg == 0){
    unsigned int o[4];
    #pragma unroll
    for (int j2 = 0; j2 < 4; j2++){
      float h0 = eluf(acc[2*j2  ]*inv + bias[cb*8 + 2*j2  ]);
      float h1 = eluf(acc[2*j2+1]*inv + bias[cb*8 + 2*j2+1]);
      o[j2] = pack2(h0, h1);
    }
    *(uint4*)(HV + (size_t)node*32 + cb*8) = make_uint4(o[0], o[1], o[2], o[3]);
  }
}

// ============== TAIL mega-kernel: rsum ∥ q ===================================
#define TB_RSUM 1024

__global__ __launch_bounds__(THREADS) void k_tail(const int* __restrict__ gptr,
    const float* __restrict__ X, float* __restrict__ gout,
    const float* __restrict__ mw, const float* __restrict__ mattd,
    float* __restrict__ q){
  int bid = blockIdx.x;
  if (bid < TB_RSUM){
    int g = bid*(THREADS/32) + (threadIdx.x >> 5);
    int c = threadIdx.x & 31;
    int gs = gptr[g], ge = gptr[g+1];
    float acc = 0.f;
    for (int n = gs; n < ge; n++) acc += X[(size_t)n*32 + c];
    gout[(size_t)g*32 + c] = fmaxf(acc, 0.f);
  } else {
    int k = threadIdx.x;
    if (k < 32){
      float acc = 0.f;
      #pragma unroll
      for (int c = 0; c < 32; c++) acc += mattd[c] * mw[c*32 + k];
      q[k] = acc;
    }
  }
}

// one readout timestep: no-max softmax over nodes of graph + weighted sum + GRU3
__global__ __launch_bounds__(THREADS) void k_rstep(const int* __restrict__ gptr,
    const float* __restrict__ anode, const bf16* __restrict__ XS,
    const float* __restrict__ q, const float* __restrict__ mbias,
    float* __restrict__ gout,
    const float* __restrict__ wih, const float* __restrict__ whh,
    const float* __restrict__ bih, const float* __restrict__ bhh){
  int g = blockIdx.x*(THREADS/32) + (threadIdx.x >> 5);
  int c = threadIdx.x & 31;
  float orow = gout[(size_t)g*32 + c];
  float ag = redsum32(orow * q[c]);
  int gs = gptr[g], ge = gptr[g+1];
  float s = 0.f;
  for (int p0 = gs; p0 < ge; p0 += 32){
    int p = p0 + c;
    bool ok = p < ge;
    float e = ok ? __expf(lrelu(anode[p] + ag)) : 0.f;
    s += redsum32(e);
  }
  float inv = 1.f/(s + 1e-16f);
  float acc = 0.f;
  int n = gs;
  for (; n + 4 <= ge; n += 4){
    float e0 = __expf(lrelu(anode[n]   + ag));
    float e1 = __expf(lrelu(anode[n+1] + ag));
    float e2 = __expf(lrelu(anode[n+2] + ag));
    float e3 = __expf(lrelu(anode[n+3] + ag));
    acc += b2f(XS[(size_t)(n  )*32 + c])*e0 + b2f(XS[(size_t)(n+1)*32 + c])*e1
         + b2f(XS[(size_t)(n+2)*32 + c])*e2 + b2f(XS[(size_t)(n+3)*32 + c])*e3;
  }
  for (; n < ge; n++)
    acc += b2f(XS[(size_t)n*32 + c]) * __expf(lrelu(anode[n] + ag));
  acc *= inv;
  float hv = eluf(acc + mbias[c]);
  gout[(size_t)g*32 + c] = gru_relu(hv, orow, c, wih, whh, bih, bhh);
}

// y = mish(out @ lin2^T + b)
__global__ __launch_bounds__(THREADS) void k_final(const float* __restrict__ out32,
    const float* __restrict__ w /*64x32*/, const float* __restrict__ b,
    float* __restrict__ y){
  int gid = blockIdx.x*THREADS + threadIdx.x;
  int g = gid >> 6, oc = gid & 63;
  const float* orow = out32 + (size_t)g*32;
  const float* wr = w + oc*32;
  float acc = b[oc];
  #pragma unroll
  for (int k = 0; k < 32; k++) acc += orow[k]*wr[k];
  float sp = fmaxf(acc, 0.f) + log1pf(expf(-fabsf(acc)));  // keep precise (final output)
  y[(size_t)g*64 + oc] = acc * tanhf(sp);
}

extern "C" void kernel_launch(void* const* d_in, const int* in_sizes, int n_in,
                              void* d_out, int out_size, void* d_ws, size_t ws_size,
                              hipStream_t stream){
  const float* x_in     = (const float*)d_in[0];
  const float* ea       = (const float*)d_in[1];
  const int*   ei       = (const int*)  d_in[2];
  const int*   batch    = (const int*)  d_in[3];
  const float* lin1_w   = (const float*)d_in[4];
  const float* lin1_b   = (const float*)d_in[5];
  const float* g_lin1_w = (const float*)d_in[6];
  const float* g_lin2_w = (const float*)d_in[7];
  const float* g_att_l  = (const float*)d_in[8];
  const float* g_att_r  = (const float*)d_in[9];
  const float* g_bias   = (const float*)d_in[10];
  const float* gru1_wih = (const float*)d_in[11];
  const float* gru1_whh = (const float*)d_in[12];
  const float* gru1_bih = (const float*)d_in[13];
  const float* gru1_bhh = (const float*)d_in[14];
  const float* a_lin_w  = (const float*)d_in[15];
  const float* a_att_src= (const float*)d_in[16];
  const float* a_att_dst= (const float*)d_in[17];
  const float* a_bias   = (const float*)d_in[18];
  const float* gru2_wih = (const float*)d_in[19];
  const float* gru2_whh = (const float*)d_in[20];
  const float* gru2_bih = (const float*)d_in[21];
  const float* gru2_bhh = (const float*)d_in[22];
  const float* m_lin_w  = (const float*)d_in[23];
  const float* m_att_src= (const float*)d_in[24];
  const float* m_att_dst= (const float*)d_in[25];
  const float* m_bias   = (const float*)d_in[26];
  const float* gru3_wih = (const float*)d_in[27];
  const float* gru3_whh = (const float*)d_in[28];
  const float* gru3_bih = (const float*)d_in[29];
  const float* gru3_bhh = (const float*)d_in[30];
  const float* lin2_w   = (const float*)d_in[31];
  const float* lin2_b   = (const float*)d_in[32];

  float* W = (float*)d_ws;
  float* X     = W;                      // NN*32 f32
  bf16*  BA    = (bf16*)(W + 8388608);   // NN*32 bf16 : u / xt / xs
  bf16*  BB    = (bf16*)(W + 12582912);  // NN*32 bf16 : v / h2
  int2*  EPK   = (int2*) (W + 16777216); // NE x (src, ea-bits)
  int*   RP1   = (int*)  (W + 20971520); // NN partial scan (dead after k_mid)
  bf16*  BC    = (bf16*) (W + 20971520); // NN*32 bf16 : h1 (written by conv1, after mid)
  int*   RANK  = (int*)  (W + 23068672); // NE within-dst ranks
  int*   ROWPTR= (int*)  (W + 25165824); // NN+1 (pad)
  int*   HIST  = (int*)  (W + 25428032); // NN
  int*   BTOT  = (int*)  (W + 25690176); // 1024
  float* NS1   = W + 25691200;           // NN : nr / al / a_node
  float* NS2   = W + 25953344;           // NN : ar
  int*   GPTR  = (int*)  (W + 26215488); // NG+1 (pad)
  float* GOUT  = W + 26223744;           // NG*32
  float* Q     = W + 26485888;           // 32

  dim3 b(THREADS);
  const int gNode  = NN/THREADS;        // 1024
  const int gNode32= NN/(THREADS/32);   // 32768
  const int gG32   = NG/(THREADS/32);   // 1024
  const int gMFMA  = NN/(16*8*4);       // 512

  // zero HIST (must precede k_front's histrank section)
  k_filli<<<gNode, b, 0, stream>>>(HIST, 0, NN);

  // FRONT: embed (MFMA) ∥ histrank (atomics) ∥ gptr
  k_front<<<FB_EMBED + FB_HIST + FB_GPTR, b, 0, stream>>>(
      x_in, lin1_w, lin1_b, g_lin1_w, g_lin2_w, g_att_r, X, BA, BB, NS1,
      ei, HIST, RANK, batch, GPTR);

  // scans; MID: final rowptr ∥ atomic-free place
  k_scan1<<<gNode, b, 0, stream>>>(HIST, RP1, BTOT);
  k_scan2<<<1, 1024, 0, stream>>>(BTOT);
  k_mid<<<MB_SCAN + NE/THREADS, b, 0, stream>>>(RP1, BTOT, ROWPTR, ei, ea, RANK, EPK);

  // GATEConv (edge score fused in-conv) + GRU1 (fused GATConv precompute)
  k_conv<<<gNode32, b, 0, stream>>>(ROWPTR, EPK, BA, g_lin1_w, g_att_l,
      nullptr, NS1, BB, g_bias, BC);
  k_gru_att<<<gMFMA, b, 0, stream>>>(BC, X, gru1_wih, gru1_whh, gru1_bih, gru1_bhh,
      a_lin_w, a_att_src, a_att_dst, BA, NS1, NS2);

  // GATConv + GRU2 (fused readout precompute)
  k_conv<<<gNode32, b, 0, stream>>>(ROWPTR, EPK, nullptr, nullptr, nullptr,
      NS1, NS2, BA, a_bias, BB);
  k_gru_att<<<gMFMA, b, 0, stream>>>(BB, X, gru2_wih, gru2_whh, gru2_bih, gru2_bhh,
      m_lin_w, m_att_src, nullptr, BA, NS1, nullptr);

  // TAIL: rsum ∥ q
  k_tail<<<TB_RSUM + 1, b, 0, stream>>>(GPTR, X, GOUT, m_lin_w, m_att_dst, Q);

  for (int t = 0; t < 2; t++){
    k_rstep<<<gG32, b, 0, stream>>>(GPTR, NS1, BA, Q, m_bias, GOUT,
        gru3_wih, gru3_whh, gru3_bih, gru3_bhh);
  }

  k_final<<<(NG*64)/THREADS, b, 0, stream>>>(GOUT, lin2_w, lin2_b, (float*)d_out);
}